// Round 6
// baseline (4753.279 us; speedup 1.0000x reference)
//
#include <hip/hip_runtime.h>
#include <hip/hip_fp16.h>
#include <hip/hip_cooperative_groups.h>

namespace cg = cooperative_groups;

#define NN 100000
#define EE 1200000
#define DD 64
#define CC 40
#define BSZ 196                          // nodes per sort bucket
#define NBK 512                          // buckets (512*196 = 100352 >= NN)
#define TCAP 3072                        // tmp capacity per bucket
#define EPB 4096                         // edges per phase-A block
#define ABLK ((EE + EPB - 1) / EPB)      // 293

// ---- persistent spmm geometry ----
// flat lane-row space (5N rows): rows[0,2N)=P01 (node=r>>1, pl=r&1),
// rows[2N,4N)=P23, rows[4N,5N)=P4. XCD k (block b -> XCD b%8, exact because the
// grid is fully co-resident): 0-2 own P01 thirds, 3-5 P23 thirds, 6-7 P4 halves.
// Each XCD's gather working set = its plane slice (<=3.2MB) -> L2-resident.
#define GRID 1024                        // 4 blocks/CU -> 32 waves/CU co-resident
#define BLK  512
#define ECAP 8192                        // staged edges/block (32KB LDS)

typedef int   v4i __attribute__((ext_vector_type(4)));
typedef float v4f __attribute__((ext_vector_type(4)));

__device__ __forceinline__ float4 ntld_f4(const float4* p) {
    v4f v = __builtin_nontemporal_load((const v4f*)p);
    return make_float4(v.x, v.y, v.z, v.w);
}
__device__ __forceinline__ void ntst_f4(float4* p, float4 f) {
    v4f v; v.x = f.x; v.y = f.y; v.z = f.z; v.w = f.w;
    __builtin_nontemporal_store(v, (v4f*)p);
}

// ---------- cursor init ----------
__global__ __launch_bounds__(512) void curinit_kernel(int* __restrict__ cursor) {
    int b = threadIdx.x;
    if (b < NBK) cursor[b] = b * TCAP;
}

// ---------- sort phase A ----------
__global__ __launch_bounds__(256) void sortA_kernel(const int* __restrict__ src,
                                                    const int* __restrict__ dst,
                                                    int* __restrict__ cursor,
                                                    int2* __restrict__ tmp) {
    __shared__ int2 stg[EPB];
    __shared__ int hist[NBK], loff[NBK], lcur[NBK], gbase[NBK];
    int t = threadIdx.x;
    long e0 = (long)blockIdx.x * EPB;
    int n = (int)((EE - e0 < EPB) ? (EE - e0) : EPB);
    for (int j = t; j < NBK; j += 256) hist[j] = 0;
    __syncthreads();
    int d[16], sx[16];
#pragma unroll
    for (int j = 0; j < 16; ++j) {
        int i = t + j * 256;
        if (i < n) {
            d[j] = dst[e0 + i];
            sx[j] = src[e0 + i];
            atomicAdd(&hist[d[j] / BSZ], 1);
        } else d[j] = -1;
    }
    __syncthreads();
    int c0 = hist[2 * t], c1 = hist[2 * t + 1];
    int s2 = c0 + c1;
    __syncthreads();
    loff[t] = s2;
    __syncthreads();
    for (int off = 1; off < 256; off <<= 1) {
        int u = (t >= off) ? loff[t - off] : 0;
        __syncthreads();
        loff[t] += u;
        __syncthreads();
    }
    int excl = loff[t] - s2;
    __syncthreads();
    loff[2 * t] = excl;          loff[2 * t + 1] = excl + c0;
    lcur[2 * t] = excl;          lcur[2 * t + 1] = excl + c0;
    gbase[2 * t]     = atomicAdd(&cursor[2 * t], c0);
    gbase[2 * t + 1] = atomicAdd(&cursor[2 * t + 1], c1);
    __syncthreads();
#pragma unroll
    for (int j = 0; j < 16; ++j) {
        if (d[j] >= 0) {
            int b = d[j] / BSZ;
            int p = atomicAdd(&lcur[b], 1);
            stg[p] = make_int2(d[j], sx[j]);
        }
    }
    __syncthreads();
    for (int i = t; i < n; i += 256) {
        int2 r = stg[i];
        int b = r.x / BSZ;
        int pos = gbase[b] + (i - loff[b]);
        if (pos < (b + 1) * TCAP) tmp[pos] = r;
    }
}

// ---------- bucket-base scan ----------
__global__ __launch_bounds__(512) void bscan_kernel(const int* __restrict__ cursor,
                                                    int* __restrict__ bbase,
                                                    int* __restrict__ row_ptr) {
    __shared__ int sm[512];
    int t = threadIdx.x;
    int v = (t < NBK) ? (cursor[t] - t * TCAP) : 0;
    sm[t] = v;
    __syncthreads();
    for (int off = 1; off < 512; off <<= 1) {
        int u = (t >= off) ? sm[t - off] : 0;
        __syncthreads();
        sm[t] += u;
        __syncthreads();
    }
    if (t < NBK) bbase[t] = sm[t] - v;
    if (t == 511) row_ptr[NN] = sm[511];
}

// ---------- sort phase B ----------
__global__ __launch_bounds__(256) void sortB_kernel(const int2* __restrict__ tmp,
                                                    const int* __restrict__ cursor,
                                                    const int* __restrict__ bbase,
                                                    float* __restrict__ dinv,
                                                    float* __restrict__ sqd,
                                                    int* __restrict__ row_ptr,
                                                    int* __restrict__ er_src) {
    __shared__ int2 se[TCAP];
    __shared__ int so[TCAP];
    __shared__ int hist[256], lcur[256];
    int b = blockIdx.x;
    int n0 = b * BSZ;
    if (n0 >= NN) return;
    int n1 = n0 + BSZ; if (n1 > NN) n1 = NN;
    int nb = n1 - n0;
    int t = threadIdx.x;
    int cnt = cursor[b] - b * TCAP;
    int base = bbase[b];
    hist[t] = 0;
    __syncthreads();
    for (int i = t; i < cnt; i += 256) {
        int2 r = tmp[b * TCAP + i];
        se[i] = r;
        atomicAdd(&hist[r.x - n0], 1);
    }
    __syncthreads();
    if (t < nb) {
        float dg = (float)(hist[t] + 1);
        dinv[n0 + t] = rsqrtf(dg);
        sqd[n0 + t]  = sqrtf(dg);
    }
    int v = hist[t];
    lcur[t] = v;
    __syncthreads();
    for (int off = 1; off < 256; off <<= 1) {
        int u = (t >= off) ? lcur[t - off] : 0;
        __syncthreads();
        lcur[t] += u;
        __syncthreads();
    }
    int excl = lcur[t] - v;
    __syncthreads();
    lcur[t] = excl;
    if (t < nb) row_ptr[n0 + t] = base + excl;
    __syncthreads();
    for (int i = t; i < cnt; i += 256) {
        int2 r = se[i];
        int ln = r.x - n0;
        int pos = atomicAdd(&lcur[ln], 1);
        so[pos] = r.y;
    }
    __syncthreads();
    for (int i = t; i < cnt; i += 256) er_src[base + i] = so[i];
}

// ---------- projection: z0 = dinv * (feat @ W^T), P-layout ----------
__global__ __launch_bounds__(256) void proj_kernel(const float4* __restrict__ feat4,
                                                   const float* __restrict__ W,
                                                   const float* __restrict__ dinv,
                                                   float4* __restrict__ z0) {
    __shared__ float smW[CC * 68];
    __shared__ float smF[64 * 68];
    __shared__ float smO[64 * 42];
    int t = threadIdx.x;
    for (int j = t; j < CC * 16; j += 256) {
        int c = j >> 4, q = j & 15;
        *(float4*)(smW + c * 68 + q * 4) = ((const float4*)W)[j];
    }
    int n0 = blockIdx.x * 64;
    for (int j = t; j < 64 * 16; j += 256) {
        int r = j >> 4, q = j & 15;
        if (n0 + r < NN)
            *(float4*)(smF + r * 68 + q * 4) = feat4[(size_t)(n0 + r) * 16 + q];
    }
    __syncthreads();
    int ln = t >> 2, c0 = (t & 3) * 10;
    int node = n0 + ln;
    float acc[10];
#pragma unroll
    for (int c = 0; c < 10; ++c) acc[c] = 0.f;
    if (node < NN) {
#pragma unroll
        for (int db = 0; db < 16; ++db) {
            float4 fv = *(const float4*)(smF + ln * 68 + db * 4);
#pragma unroll
            for (int c = 0; c < 10; ++c) {
                float4 wv = *(const float4*)(smW + (c0 + c) * 68 + db * 4);
                acc[c] = fmaf(fv.x, wv.x, acc[c]);
                acc[c] = fmaf(fv.y, wv.y, acc[c]);
                acc[c] = fmaf(fv.z, wv.z, acc[c]);
                acc[c] = fmaf(fv.w, wv.w, acc[c]);
            }
        }
    }
#pragma unroll
    for (int c = 0; c < 10; ++c) smO[ln * 42 + c0 + c] = acc[c];
    __syncthreads();
    for (int j = t; j < 64 * 5; j += 256) {
        int r = j & 63, q = j >> 6;
        int g = n0 + r;
        if (g < NN) {
            float dv = dinv[g];
            const float* s = smO + r * 42 + q * 8;
            float4 ov;
            __half2* op = (__half2*)&ov;
            op[0] = __floats2half2_rn(dv * s[0], dv * s[1]);
            op[1] = __floats2half2_rn(dv * s[2], dv * s[3]);
            op[2] = __floats2half2_rn(dv * s[4], dv * s[5]);
            op[3] = __floats2half2_rn(dv * s[6], dv * s[7]);
            size_t idx = (q < 2) ? ((size_t)g * 2 + q)
                       : (q < 4) ? ((size_t)2 * NN + (size_t)g * 2 + (q - 2))
                                 : ((size_t)4 * NN + g);
            z0[idx] = ov;
        }
    }
}

// ---------- persistent spmm ----------
struct A8 { float a0, a1, a2, a3, a4, a5, a6, a7; };

__device__ __forceinline__ A8 seedA(float4 v) {
    const __half2* h = (const __half2*)&v;
    float2 f0 = __half22float2(h[0]), f1 = __half22float2(h[1]);
    float2 f2 = __half22float2(h[2]), f3 = __half22float2(h[3]);
    A8 A; A.a0 = f0.x; A.a1 = f0.y; A.a2 = f1.x; A.a3 = f1.y;
    A.a4 = f2.x; A.a5 = f2.y; A.a6 = f3.x; A.a7 = f3.y;
    return A;
}
__device__ __forceinline__ void acc8(A8& A, float4 v) {
    const __half2* h = (const __half2*)&v;
    float2 f0 = __half22float2(h[0]), f1 = __half22float2(h[1]);
    float2 f2 = __half22float2(h[2]), f3 = __half22float2(h[3]);
    A.a0 += f0.x; A.a1 += f0.y; A.a2 += f1.x; A.a3 += f1.y;
    A.a4 += f2.x; A.a5 += f2.y; A.a6 += f3.x; A.a7 += f3.y;
}

__device__ __forceinline__ void gath(A8& A, const float4* __restrict__ xp, int sh,
                                     const int* __restrict__ ix, int b, int e) {
    int i = b;
    for (; i + 4 <= e; i += 4) {
        int s0 = ix[i], s1 = ix[i + 1], s2 = ix[i + 2], s3 = ix[i + 3];
        float4 v0 = xp[(size_t)s0 << sh];
        float4 v1 = xp[(size_t)s1 << sh];
        float4 v2 = xp[(size_t)s2 << sh];
        float4 v3 = xp[(size_t)s3 << sh];
        acc8(A, v0); acc8(A, v1); acc8(A, v2); acc8(A, v3);
    }
    for (; i < e; ++i) {
        float4 v = xp[(size_t)ix[i] << sh];
        acc8(A, v);
    }
}

__device__ __forceinline__ void prop_one(
    const float4* __restrict__ xs, float4* __restrict__ xd,
    size_t ad, size_t pb, int sh,
    const int* __restrict__ ix, int b, int e, float w2) {
    const float4* xp = xs + pb;
    A8 A = seedA(xs[ad]);
    gath(A, xp, sh, ix, b, e);
    float4 ov; __half2* op = (__half2*)&ov;
    op[0] = __floats2half2_rn(w2 * A.a0, w2 * A.a1);
    op[1] = __floats2half2_rn(w2 * A.a2, w2 * A.a3);
    op[2] = __floats2half2_rn(w2 * A.a4, w2 * A.a5);
    op[3] = __floats2half2_rn(w2 * A.a6, w2 * A.a7);
    xd[ad] = ov;   // normal store: seeds the home XCD's L2 for next step
}

__device__ __forceinline__ void final_one(
    const float4* __restrict__ z15, const float4* __restrict__ z13,
    const float4* __restrict__ z14, const float4* __restrict__ z0,
    size_t ad, size_t pb, int sh,
    const int* __restrict__ ix, int b, int e,
    float di, float sq, int g, int pOut,
    const float* __restrict__ bias, float* __restrict__ outp) {
    const float4* xp = z15 + pb;
    A8 S = seedA(z15[ad]);
    A8 A = S;
    gath(A, xp, sh, ix, b, e);
    const float C16 = 0.95f / 16.0f;
    const float C15 = 0.95f / 256.0f;
    const float C14 = 0.95f / 4096.0f;
    const float C13 = 0.95f / 65536.0f;
    const float FC  = 0.05f / 15.0f;
    A8 T14 = seedA(ntld_f4(z14 + ad));
    A8 T13 = seedA(ntld_f4(z13 + ad));
    A8 T0  = seedA(ntld_f4(z0 + ad));
    float cd = C16 * di;
    float o0 = fmaf(sq, C15 * S.a0 + C14 * T14.a0 + C13 * T13.a0 + FC * T0.a0, cd * A.a0);
    float o1 = fmaf(sq, C15 * S.a1 + C14 * T14.a1 + C13 * T13.a1 + FC * T0.a1, cd * A.a1);
    float o2 = fmaf(sq, C15 * S.a2 + C14 * T14.a2 + C13 * T13.a2 + FC * T0.a2, cd * A.a2);
    float o3 = fmaf(sq, C15 * S.a3 + C14 * T14.a3 + C13 * T13.a3 + FC * T0.a3, cd * A.a3);
    float o4 = fmaf(sq, C15 * S.a4 + C14 * T14.a4 + C13 * T13.a4 + FC * T0.a4, cd * A.a4);
    float o5 = fmaf(sq, C15 * S.a5 + C14 * T14.a5 + C13 * T13.a5 + FC * T0.a5, cd * A.a5);
    float o6 = fmaf(sq, C15 * S.a6 + C14 * T14.a6 + C13 * T13.a6 + FC * T0.a6, cd * A.a6);
    float o7 = fmaf(sq, C15 * S.a7 + C14 * T14.a7 + C13 * T13.a7 + FC * T0.a7, cd * A.a7);
    const float4* b4 = (const float4*)(bias + pOut * 8);
    float4 bb0 = b4[0], bb1 = b4[1];
    float4* op = (float4*)(outp + (size_t)g * CC + pOut * 8);
    ntst_f4(op,     make_float4(o0 + bb0.x, o1 + bb0.y, o2 + bb0.z, o3 + bb0.w));
    ntst_f4(op + 1, make_float4(o4 + bb1.x, o5 + bb1.y, o6 + bb1.z, o7 + bb1.w));
}

__global__ __launch_bounds__(BLK, 8) void spmm_persist(
    const float4* __restrict__ z0, float4* __restrict__ xa, float4* __restrict__ xb,
    float4* __restrict__ z13, float4* __restrict__ z14, float4* __restrict__ z15,
    const int* __restrict__ row_ptr, const int* __restrict__ es,
    const float* __restrict__ dinv, const float* __restrict__ sqd,
    const float* __restrict__ bias, float* __restrict__ outp,
    int sBeg, int sEnd) {
    __shared__ __align__(16) int sidx[ECAP + 8];
    int xcd = blockIdx.x & 7, idx = blockIdx.x >> 3, t = threadIdx.x;
    int R0, R1, gbRow, sh, grpP; size_t gbase;
    if (xcd < 3)      { gbRow = 0;      R0 = xcd * 66667;                R1 = (xcd == 2) ? 200000 : (R0 + 66667); gbase = 0;              sh = 1; grpP = 0; }
    else if (xcd < 6) { gbRow = 200000; R0 = 200000 + (xcd - 3) * 66667; R1 = (xcd == 5) ? 400000 : (R0 + 66667); gbase = 2 * (size_t)NN; sh = 1; grpP = 2; }
    else              { gbRow = 400000; R0 = 400000 + (xcd - 6) * 50000; R1 = R0 + 50000;                         gbase = 4 * (size_t)NN; sh = 0; grpP = 4; }
    int rs = R0 + idx * BLK;
    int re = rs + BLK; if (re > R1) re = R1;
    // nominal row
    int r1 = rs + t;
    bool act1 = r1 < re;
    int lr1 = act1 ? (r1 - gbRow) : 0;
    int n1 = (sh == 1) ? (lr1 >> 1) : lr1;
    int pl1 = (sh == 1) ? (lr1 & 1) : 0;
    size_t ad1 = gbase + (((size_t)n1) << sh) + pl1;
    size_t pb1 = gbase + pl1;
    int beg1 = 0, end1 = 0; float w21 = 0.f, di1 = 0.f, sq1 = 0.f;
    if (act1) { beg1 = row_ptr[n1]; end1 = row_ptr[n1 + 1]; di1 = dinv[n1]; w21 = di1 * di1; sq1 = sqd[n1]; }
    // overflow row (per-XCD rows beyond 128*BLK nominal capacity)
    int OV = R1 - R0 - (GRID / 8) * BLK;
    int gix = idx * BLK + t;
    bool act2 = (OV > 0) && (gix < OV);
    int lr2 = act2 ? (R0 + (GRID / 8) * BLK + gix - gbRow) : 0;
    int n2 = (sh == 1) ? (lr2 >> 1) : lr2;
    int pl2 = (sh == 1) ? (lr2 & 1) : 0;
    size_t ad2 = gbase + (((size_t)n2) << sh) + pl2;
    size_t pb2 = gbase + pl2;
    int beg2 = 0, end2 = 0; float w22 = 0.f, di2 = 0.f, sq2 = 0.f;
    if (act2) { beg2 = row_ptr[n2]; end2 = row_ptr[n2 + 1]; di2 = dinv[n2]; w22 = di2 * di2; sq2 = sqd[n2]; }
    // stage this block's edge window into LDS ONCE (reused by all 16 steps)
    int A0 = 0; bool fits = false;
    if (rs < re) {
        int nodeB, nodeE;
        if (sh == 1) { nodeB = (rs - gbRow) >> 1; nodeE = ((re - 1 - gbRow) >> 1) + 1; }
        else         { nodeB = rs - gbRow;        nodeE = re - gbRow; }
        int EB = row_ptr[nodeB], EL = row_ptr[nodeE];
        A0 = EB & ~3;
        fits = (EL - A0) <= ECAP;
        if (fits) {
            for (int i = A0 + t * 4; i < EL; i += BLK * 4)
                *(v4i*)(sidx + (i - A0)) = *(const v4i*)(es + i);
        }
    }
    __syncthreads();

    cg::grid_group grid = cg::this_grid();
    for (int s = sBeg; s < sEnd; ++s) {
        if (s > sBeg) { __threadfence(); grid.sync(); }
        if (s < 15) {
            const float4* xs; float4* xd;
            if (s == 0)       { xs = z0;  xd = xa; }
            else if (s < 12)  { xs = (s & 1) ? xa : xb; xd = (s & 1) ? xb : xa; }
            else if (s == 12) { xs = xb;  xd = z13; }
            else if (s == 13) { xs = z13; xd = z14; }
            else              { xs = z14; xd = z15; }
            if (act1) {
                if (fits) prop_one(xs, xd, ad1, pb1, sh, sidx, beg1 - A0, end1 - A0, w21);
                else      prop_one(xs, xd, ad1, pb1, sh, es,   beg1,      end1,      w21);
            }
            if (act2)     prop_one(xs, xd, ad2, pb2, sh, es,   beg2,      end2,      w22);
        } else {
            if (act1) {
                if (fits) final_one(z15, z13, z14, z0, ad1, pb1, sh, sidx, beg1 - A0, end1 - A0,
                                    di1, sq1, n1, grpP + pl1, bias, outp);
                else      final_one(z15, z13, z14, z0, ad1, pb1, sh, es,   beg1,      end1,
                                    di1, sq1, n1, grpP + pl1, bias, outp);
            }
            if (act2)     final_one(z15, z13, z14, z0, ad2, pb2, sh, es,   beg2,      end2,
                                    di2, sq2, n2, grpP + pl2, bias, outp);
        }
    }
}

extern "C" void kernel_launch(void* const* d_in, const int* in_sizes, int n_in,
                              void* d_out, int out_size, void* d_ws, size_t ws_size,
                              hipStream_t stream) {
    const float* feat = (const float*)d_in[0];
    const float* W    = (const float*)d_in[1];
    const float* b    = (const float*)d_in[2];
    const int*   src  = (const int*)d_in[3];
    const int*   dst  = (const int*)d_in[4];
    float* out = (float*)d_out;

    char* p = (char*)d_ws;
    auto alloc = [&](size_t bytes) {
        char* r = p;
        p += (bytes + 255) & ~(size_t)255;
        return r;
    };
    float*   dinv    = (float*)alloc((size_t)NN * sizeof(float));
    float*   sqd     = (float*)alloc((size_t)NN * sizeof(float));
    int*     row_ptr = (int*)alloc((size_t)(NN + 1) * sizeof(int));
    int*     cursor  = (int*)alloc((size_t)NBK * sizeof(int));
    int*     bbase   = (int*)alloc((size_t)NBK * sizeof(int));
    int2*    tmp     = (int2*)alloc((size_t)NBK * TCAP * sizeof(int2));
    int*     er_src  = (int*)alloc((size_t)EE * sizeof(int) + 64);
    float4*  z0      = (float4*)alloc((size_t)NN * 5 * sizeof(float4));
    float4*  xa      = (float4*)alloc((size_t)NN * 5 * sizeof(float4));
    float4*  xb      = (float4*)alloc((size_t)NN * 5 * sizeof(float4));
    float4*  z13     = (float4*)alloc((size_t)NN * 5 * sizeof(float4));
    float4*  z14     = (float4*)alloc((size_t)NN * 5 * sizeof(float4));
    float4*  z15     = (float4*)alloc((size_t)NN * 5 * sizeof(float4));

    curinit_kernel<<<1, 512, 0, stream>>>(cursor);
    sortA_kernel<<<ABLK, 256, 0, stream>>>(src, dst, cursor, tmp);
    bscan_kernel<<<1, 512, 0, stream>>>(cursor, bbase, row_ptr);
    sortB_kernel<<<NBK, 256, 0, stream>>>(tmp, cursor, bbase, dinv, sqd, row_ptr, er_src);
    proj_kernel<<<(NN + 63) / 64, 256, 0, stream>>>((const float4*)feat, W, dinv, z0);

    // one persistent cooperative kernel: 15 prop steps + final, grid-synced
    {
        const float4* a_z0 = z0; float4* a_xa = xa; float4* a_xb = xb;
        float4* a_z13 = z13; float4* a_z14 = z14; float4* a_z15 = z15;
        const int* a_rp = row_ptr; const int* a_es = er_src;
        const float* a_di = dinv; const float* a_sq = sqd;
        const float* a_b = b; float* a_out = out;
        int sb = 0, se = 16;
        void* args[] = { &a_z0, &a_xa, &a_xb, &a_z13, &a_z14, &a_z15,
                         &a_rp, &a_es, &a_di, &a_sq, &a_b, &a_out, &sb, &se };
        hipError_t ce = hipLaunchCooperativeKernel((const void*)spmm_persist,
                                                   dim3(GRID), dim3(BLK), args, 0, stream);
        if (ce != hipSuccess) {
            (void)hipGetLastError();   // clear; fall back to 16 single-step launches
            for (int s = 0; s < 16; ++s)
                spmm_persist<<<GRID, BLK, 0, stream>>>(z0, xa, xb, z13, z14, z15,
                                                       row_ptr, er_src, dinv, sqd,
                                                       b, out, s, s + 1);
        }
    }
}

// Round 7
// 2920.218 us; speedup vs baseline: 1.6277x; 1.6277x over previous
//
#include <hip/hip_runtime.h>
#include <hip/hip_fp16.h>
#include <hip/hip_cooperative_groups.h>

namespace cg = cooperative_groups;

#define NN 100000
#define EE 1200000
#define DD 64
#define CC 40
#define BSZ 196                          // nodes per sort bucket
#define NBK 512                          // buckets (512*196 = 100352 >= NN)
#define TCAP 3072                        // tmp capacity per bucket
#define EPB 4096                         // edges per phase-A block
#define ABLK ((EE + EPB - 1) / EPB)      // 293

// flat lane-row space (5N rows of float4): rows[0,2N)=P01 (node=lr>>1, pl=lr&1),
// rows[2N,4N)=P23, rows[4N,5N)=P4. Address of a row in x == row index.
// XCD k (block b -> XCD b%8; GRID=512 is fully co-resident at 2 blocks/CU so the
// mapping is exact for the whole kernel): XCD 0-2 P01 thirds, 3-5 P23 thirds,
// 6-7 P4 halves. Per-XCD gather slice <=3.2MB -> L2-resident (r3/r5 FETCH=44MB
// confirms mostly-hit). Edge windows staged in LDS ONCE, reused by all 16 steps.
#define GRID 512                         // 2 blocks/CU, co-resident
#define BLK  512
#define ECAP 16384                       // staged edges/block (64KB LDS)

typedef int   v4i __attribute__((ext_vector_type(4)));
typedef float v4f __attribute__((ext_vector_type(4)));

__device__ __forceinline__ float4 ntld_f4(const float4* p) {
    v4f v = __builtin_nontemporal_load((const v4f*)p);
    return make_float4(v.x, v.y, v.z, v.w);
}
__device__ __forceinline__ void ntst_f4(float4* p, float4 f) {
    v4f v; v.x = f.x; v.y = f.y; v.z = f.z; v.w = f.w;
    __builtin_nontemporal_store(v, (v4f*)p);
}

// ---------- cursor init ----------
__global__ __launch_bounds__(512) void curinit_kernel(int* __restrict__ cursor) {
    int b = threadIdx.x;
    if (b < NBK) cursor[b] = b * TCAP;
}

// ---------- sort phase A ----------
__global__ __launch_bounds__(256) void sortA_kernel(const int* __restrict__ src,
                                                    const int* __restrict__ dst,
                                                    int* __restrict__ cursor,
                                                    int2* __restrict__ tmp) {
    __shared__ int2 stg[EPB];
    __shared__ int hist[NBK], loff[NBK], lcur[NBK], gbase[NBK];
    int t = threadIdx.x;
    long e0 = (long)blockIdx.x * EPB;
    int n = (int)((EE - e0 < EPB) ? (EE - e0) : EPB);
    for (int j = t; j < NBK; j += 256) hist[j] = 0;
    __syncthreads();
    int d[16], sx[16];
#pragma unroll
    for (int j = 0; j < 16; ++j) {
        int i = t + j * 256;
        if (i < n) {
            d[j] = dst[e0 + i];
            sx[j] = src[e0 + i];
            atomicAdd(&hist[d[j] / BSZ], 1);
        } else d[j] = -1;
    }
    __syncthreads();
    int c0 = hist[2 * t], c1 = hist[2 * t + 1];
    int s2 = c0 + c1;
    __syncthreads();
    loff[t] = s2;
    __syncthreads();
    for (int off = 1; off < 256; off <<= 1) {
        int u = (t >= off) ? loff[t - off] : 0;
        __syncthreads();
        loff[t] += u;
        __syncthreads();
    }
    int excl = loff[t] - s2;
    __syncthreads();
    loff[2 * t] = excl;          loff[2 * t + 1] = excl + c0;
    lcur[2 * t] = excl;          lcur[2 * t + 1] = excl + c0;
    gbase[2 * t]     = atomicAdd(&cursor[2 * t], c0);
    gbase[2 * t + 1] = atomicAdd(&cursor[2 * t + 1], c1);
    __syncthreads();
#pragma unroll
    for (int j = 0; j < 16; ++j) {
        if (d[j] >= 0) {
            int b = d[j] / BSZ;
            int p = atomicAdd(&lcur[b], 1);
            stg[p] = make_int2(d[j], sx[j]);
        }
    }
    __syncthreads();
    for (int i = t; i < n; i += 256) {
        int2 r = stg[i];
        int b = r.x / BSZ;
        int pos = gbase[b] + (i - loff[b]);
        if (pos < (b + 1) * TCAP) tmp[pos] = r;
    }
}

// ---------- bucket-base scan ----------
__global__ __launch_bounds__(512) void bscan_kernel(const int* __restrict__ cursor,
                                                    int* __restrict__ bbase,
                                                    int* __restrict__ row_ptr) {
    __shared__ int sm[512];
    int t = threadIdx.x;
    int v = (t < NBK) ? (cursor[t] - t * TCAP) : 0;
    sm[t] = v;
    __syncthreads();
    for (int off = 1; off < 512; off <<= 1) {
        int u = (t >= off) ? sm[t - off] : 0;
        __syncthreads();
        sm[t] += u;
        __syncthreads();
    }
    if (t < NBK) bbase[t] = sm[t] - v;
    if (t == 511) row_ptr[NN] = sm[511];
}

// ---------- sort phase B ----------
__global__ __launch_bounds__(256) void sortB_kernel(const int2* __restrict__ tmp,
                                                    const int* __restrict__ cursor,
                                                    const int* __restrict__ bbase,
                                                    float* __restrict__ dinv,
                                                    float* __restrict__ sqd,
                                                    int* __restrict__ row_ptr,
                                                    int* __restrict__ er_src) {
    __shared__ int2 se[TCAP];
    __shared__ int so[TCAP];
    __shared__ int hist[256], lcur[256];
    int b = blockIdx.x;
    int n0 = b * BSZ;
    if (n0 >= NN) return;
    int n1 = n0 + BSZ; if (n1 > NN) n1 = NN;
    int nb = n1 - n0;
    int t = threadIdx.x;
    int cnt = cursor[b] - b * TCAP;
    int base = bbase[b];
    hist[t] = 0;
    __syncthreads();
    for (int i = t; i < cnt; i += 256) {
        int2 r = tmp[b * TCAP + i];
        se[i] = r;
        atomicAdd(&hist[r.x - n0], 1);
    }
    __syncthreads();
    if (t < nb) {
        float dg = (float)(hist[t] + 1);
        dinv[n0 + t] = rsqrtf(dg);
        sqd[n0 + t]  = sqrtf(dg);
    }
    int v = hist[t];
    lcur[t] = v;
    __syncthreads();
    for (int off = 1; off < 256; off <<= 1) {
        int u = (t >= off) ? lcur[t - off] : 0;
        __syncthreads();
        lcur[t] += u;
        __syncthreads();
    }
    int excl = lcur[t] - v;
    __syncthreads();
    lcur[t] = excl;
    if (t < nb) row_ptr[n0 + t] = base + excl;
    __syncthreads();
    for (int i = t; i < cnt; i += 256) {
        int2 r = se[i];
        int ln = r.x - n0;
        int pos = atomicAdd(&lcur[ln], 1);
        so[pos] = r.y;
    }
    __syncthreads();
    for (int i = t; i < cnt; i += 256) er_src[base + i] = so[i];
}

// ---------- projection: z0 = dinv * (feat @ W^T), P-layout ----------
__global__ __launch_bounds__(256) void proj_kernel(const float4* __restrict__ feat4,
                                                   const float* __restrict__ W,
                                                   const float* __restrict__ dinv,
                                                   float4* __restrict__ z0) {
    __shared__ float smW[CC * 68];
    __shared__ float smF[64 * 68];
    __shared__ float smO[64 * 42];
    int t = threadIdx.x;
    for (int j = t; j < CC * 16; j += 256) {
        int c = j >> 4, q = j & 15;
        *(float4*)(smW + c * 68 + q * 4) = ((const float4*)W)[j];
    }
    int n0 = blockIdx.x * 64;
    for (int j = t; j < 64 * 16; j += 256) {
        int r = j >> 4, q = j & 15;
        if (n0 + r < NN)
            *(float4*)(smF + r * 68 + q * 4) = feat4[(size_t)(n0 + r) * 16 + q];
    }
    __syncthreads();
    int ln = t >> 2, c0 = (t & 3) * 10;
    int node = n0 + ln;
    float acc[10];
#pragma unroll
    for (int c = 0; c < 10; ++c) acc[c] = 0.f;
    if (node < NN) {
#pragma unroll
        for (int db = 0; db < 16; ++db) {
            float4 fv = *(const float4*)(smF + ln * 68 + db * 4);
#pragma unroll
            for (int c = 0; c < 10; ++c) {
                float4 wv = *(const float4*)(smW + (c0 + c) * 68 + db * 4);
                acc[c] = fmaf(fv.x, wv.x, acc[c]);
                acc[c] = fmaf(fv.y, wv.y, acc[c]);
                acc[c] = fmaf(fv.z, wv.z, acc[c]);
                acc[c] = fmaf(fv.w, wv.w, acc[c]);
            }
        }
    }
#pragma unroll
    for (int c = 0; c < 10; ++c) smO[ln * 42 + c0 + c] = acc[c];
    __syncthreads();
    for (int j = t; j < 64 * 5; j += 256) {
        int r = j & 63, q = j >> 6;
        int g = n0 + r;
        if (g < NN) {
            float dv = dinv[g];
            const float* s = smO + r * 42 + q * 8;
            float4 ov;
            __half2* op = (__half2*)&ov;
            op[0] = __floats2half2_rn(dv * s[0], dv * s[1]);
            op[1] = __floats2half2_rn(dv * s[2], dv * s[3]);
            op[2] = __floats2half2_rn(dv * s[4], dv * s[5]);
            op[3] = __floats2half2_rn(dv * s[6], dv * s[7]);
            size_t idx = (q < 2) ? ((size_t)g * 2 + q)
                       : (q < 4) ? ((size_t)2 * NN + (size_t)g * 2 + (q - 2))
                                 : ((size_t)4 * NN + g);
            z0[idx] = ov;
        }
    }
}

// ---------- persistent spmm ----------
struct A8 { float a0, a1, a2, a3, a4, a5, a6, a7; };

__device__ __forceinline__ A8 seedA(float4 v) {
    const __half2* h = (const __half2*)&v;
    float2 f0 = __half22float2(h[0]), f1 = __half22float2(h[1]);
    float2 f2 = __half22float2(h[2]), f3 = __half22float2(h[3]);
    A8 A; A.a0 = f0.x; A.a1 = f0.y; A.a2 = f1.x; A.a3 = f1.y;
    A.a4 = f2.x; A.a5 = f2.y; A.a6 = f3.x; A.a7 = f3.y;
    return A;
}
__device__ __forceinline__ void acc8(A8& A, float4 v) {
    const __half2* h = (const __half2*)&v;
    float2 f0 = __half22float2(h[0]), f1 = __half22float2(h[1]);
    float2 f2 = __half22float2(h[2]), f3 = __half22float2(h[3]);
    A.a0 += f0.x; A.a1 += f0.y; A.a2 += f1.x; A.a3 += f1.y;
    A.a4 += f2.x; A.a5 += f2.y; A.a6 += f3.x; A.a7 += f3.y;
}

// 8/4/1-tier gather: up to 8 loads in flight/lane
__device__ __forceinline__ void gath(A8& A, const float4* __restrict__ xp, int sh,
                                     const int* __restrict__ ix, int b, int e) {
    int i = b;
    for (; i + 8 <= e; i += 8) {
        int s0 = ix[i],     s1 = ix[i + 1], s2 = ix[i + 2], s3 = ix[i + 3];
        int s4 = ix[i + 4], s5 = ix[i + 5], s6 = ix[i + 6], s7 = ix[i + 7];
        float4 v0 = xp[(size_t)s0 << sh];
        float4 v1 = xp[(size_t)s1 << sh];
        float4 v2 = xp[(size_t)s2 << sh];
        float4 v3 = xp[(size_t)s3 << sh];
        float4 v4 = xp[(size_t)s4 << sh];
        float4 v5 = xp[(size_t)s5 << sh];
        float4 v6 = xp[(size_t)s6 << sh];
        float4 v7 = xp[(size_t)s7 << sh];
        acc8(A, v0); acc8(A, v1); acc8(A, v2); acc8(A, v3);
        acc8(A, v4); acc8(A, v5); acc8(A, v6); acc8(A, v7);
    }
    if (i + 4 <= e) {
        int s0 = ix[i], s1 = ix[i + 1], s2 = ix[i + 2], s3 = ix[i + 3];
        float4 v0 = xp[(size_t)s0 << sh];
        float4 v1 = xp[(size_t)s1 << sh];
        float4 v2 = xp[(size_t)s2 << sh];
        float4 v3 = xp[(size_t)s3 << sh];
        acc8(A, v0); acc8(A, v1); acc8(A, v2); acc8(A, v3);
        i += 4;
    }
    for (; i < e; ++i) acc8(A, xp[(size_t)ix[i] << sh]);
}

__global__ __launch_bounds__(BLK, 4) void spmm_persist(
    const float4* __restrict__ z0, float4* __restrict__ xa, float4* __restrict__ xb,
    float4* __restrict__ z13, float4* __restrict__ z14, float4* __restrict__ z15,
    const int* __restrict__ row_ptr, const int* __restrict__ es,
    const float* __restrict__ dinv, const float* __restrict__ sqd,
    const float* __restrict__ bias, float* __restrict__ outp,
    int sBeg, int sEnd) {
    __shared__ __align__(16) int sidx[ECAP + 8];
    int xcd = (int)blockIdx.x & 7, j = (int)blockIdx.x >> 3, t = threadIdx.x;
    int base, R0, R1, sh, grpP;
    if (xcd < 6) {
        int kk = (xcd < 3) ? xcd : xcd - 3;
        base = (xcd < 3) ? 0 : 200000;
        R0 = base + ((kk == 0) ? 0 : (kk == 1) ? 66668 : 133336);
        R1 = base + ((kk == 0) ? 66668 : (kk == 1) ? 133336 : 200000);
        sh = 1; grpP = (xcd < 3) ? 0 : 2;
    } else {
        base = 400000;
        R0 = 400000 + (xcd - 6) * 50000; R1 = R0 + 50000;
        sh = 0; grpP = 4;
    }
    int RPB = ((R1 - R0) + 63) >> 6;
    if (sh) RPB = (RPB + 1) & ~1;          // never split a node's plane pair
    int rs = R0 + j * RPB;
    int re = rs + RPB; if (re > R1) re = R1;

    // per-thread rows (<=3, static)
    int  rr[3], bb[3], ee[3];
    float ww[3];
    bool aa[3];
#pragma unroll
    for (int i = 0; i < 3; ++i) {
        int r = rs + t + i * BLK;
        bool a = r < re;
        aa[i] = a; rr[i] = r;
        int n = a ? ((r - base) >> sh) : 0;
        bb[i] = a ? row_ptr[n] : 0;
        ee[i] = a ? row_ptr[n + 1] : 0;
        float di = a ? dinv[n] : 0.f;
        ww[i] = di * di;
    }

    // stage this block's edge window into LDS ONCE (reused by all 16 steps)
    int lrs = rs - base, lre = re - base;
    int nodeB = lrs >> sh;
    int nodeE = ((lre - 1) >> sh) + 1;
    int EB = row_ptr[nodeB], EL = row_ptr[nodeE];
    int A0 = EB & ~3;
    bool fits = (EL - A0) <= ECAP;
    if (fits) {
        for (int i = A0 + t * 4; i < EL; i += BLK * 4)
            *(v4i*)(sidx + (i - A0)) = *(const v4i*)(es + i);
    }
    __syncthreads();
    const int* ix = fits ? (const int*)sidx : es;
    int off = fits ? A0 : 0;

    cg::grid_group grid = cg::this_grid();
    for (int s = sBeg; s < sEnd; ++s) {
        if (s > sBeg) { __threadfence(); grid.sync(); }
        if (s < 15) {
            const float4* xs; float4* xd;
            if (s == 0)       { xs = z0;  xd = xa; }
            else if (s < 12)  { xs = (s & 1) ? xa : xb; xd = (s & 1) ? xb : xa; }
            else if (s == 12) { xs = xb;  xd = z13; }
            else if (s == 13) { xs = z13; xd = z14; }
            else              { xs = z14; xd = z15; }
#pragma unroll
            for (int i = 0; i < 3; ++i) {
                if (!aa[i]) continue;
                int r = rr[i];
                size_t pb = (size_t)base + (sh ? (r & 1) : 0);
                A8 A = seedA(xs[r]);
                gath(A, xs + pb, sh, ix, bb[i] - off, ee[i] - off);
                float w2 = ww[i];
                float4 ov; __half2* op = (__half2*)&ov;
                op[0] = __floats2half2_rn(w2 * A.a0, w2 * A.a1);
                op[1] = __floats2half2_rn(w2 * A.a2, w2 * A.a3);
                op[2] = __floats2half2_rn(w2 * A.a4, w2 * A.a5);
                op[3] = __floats2half2_rn(w2 * A.a6, w2 * A.a7);
                xd[r] = ov;   // normal store: seeds home XCD's L2 for next step
            }
        } else {
            const float C16 = 0.95f / 16.0f;
            const float C15 = 0.95f / 256.0f;
            const float C14 = 0.95f / 4096.0f;
            const float C13 = 0.95f / 65536.0f;
            const float FC  = 0.05f / 15.0f;
#pragma unroll
            for (int i = 0; i < 3; ++i) {
                if (!aa[i]) continue;
                int r = rr[i];
                int n = (r - base) >> sh;
                int pl = sh ? (r & 1) : 0;
                size_t pb = (size_t)base + pl;
                A8 S = seedA(z15[r]);
                A8 A = S;
                gath(A, z15 + pb, sh, ix, bb[i] - off, ee[i] - off);
                float di = dinv[n], sq = sqd[n];
                A8 T14 = seedA(ntld_f4(z14 + r));
                A8 T13 = seedA(ntld_f4(z13 + r));
                A8 T0  = seedA(ntld_f4(z0  + r));
                float cd = C16 * di;
                float o0 = fmaf(sq, C15 * S.a0 + C14 * T14.a0 + C13 * T13.a0 + FC * T0.a0, cd * A.a0);
                float o1 = fmaf(sq, C15 * S.a1 + C14 * T14.a1 + C13 * T13.a1 + FC * T0.a1, cd * A.a1);
                float o2 = fmaf(sq, C15 * S.a2 + C14 * T14.a2 + C13 * T13.a2 + FC * T0.a2, cd * A.a2);
                float o3 = fmaf(sq, C15 * S.a3 + C14 * T14.a3 + C13 * T13.a3 + FC * T0.a3, cd * A.a3);
                float o4 = fmaf(sq, C15 * S.a4 + C14 * T14.a4 + C13 * T13.a4 + FC * T0.a4, cd * A.a4);
                float o5 = fmaf(sq, C15 * S.a5 + C14 * T14.a5 + C13 * T13.a5 + FC * T0.a5, cd * A.a5);
                float o6 = fmaf(sq, C15 * S.a6 + C14 * T14.a6 + C13 * T13.a6 + FC * T0.a6, cd * A.a6);
                float o7 = fmaf(sq, C15 * S.a7 + C14 * T14.a7 + C13 * T13.a7 + FC * T0.a7, cd * A.a7);
                int pOut = grpP + pl;
                const float4* b4 = (const float4*)(bias + pOut * 8);
                float4 bb0 = b4[0], bb1 = b4[1];
                float4* op = (float4*)(outp + (size_t)n * CC + pOut * 8);
                ntst_f4(op,     make_float4(o0 + bb0.x, o1 + bb0.y, o2 + bb0.z, o3 + bb0.w));
                ntst_f4(op + 1, make_float4(o4 + bb1.x, o5 + bb1.y, o6 + bb1.z, o7 + bb1.w));
            }
        }
    }
}

extern "C" void kernel_launch(void* const* d_in, const int* in_sizes, int n_in,
                              void* d_out, int out_size, void* d_ws, size_t ws_size,
                              hipStream_t stream) {
    const float* feat = (const float*)d_in[0];
    const float* W    = (const float*)d_in[1];
    const float* b    = (const float*)d_in[2];
    const int*   src  = (const int*)d_in[3];
    const int*   dst  = (const int*)d_in[4];
    float* out = (float*)d_out;

    char* p = (char*)d_ws;
    auto alloc = [&](size_t bytes) {
        char* r = p;
        p += (bytes + 255) & ~(size_t)255;
        return r;
    };
    float*   dinv    = (float*)alloc((size_t)NN * sizeof(float));
    float*   sqd     = (float*)alloc((size_t)NN * sizeof(float));
    int*     row_ptr = (int*)alloc((size_t)(NN + 1) * sizeof(int));
    int*     cursor  = (int*)alloc((size_t)NBK * sizeof(int));
    int*     bbase   = (int*)alloc((size_t)NBK * sizeof(int));
    int2*    tmp     = (int2*)alloc((size_t)NBK * TCAP * sizeof(int2));
    int*     er_src  = (int*)alloc((size_t)EE * sizeof(int) + 64);
    float4*  z0      = (float4*)alloc((size_t)NN * 5 * sizeof(float4));
    float4*  xa      = (float4*)alloc((size_t)NN * 5 * sizeof(float4));
    float4*  xb      = (float4*)alloc((size_t)NN * 5 * sizeof(float4));
    float4*  z13     = (float4*)alloc((size_t)NN * 5 * sizeof(float4));
    float4*  z14     = (float4*)alloc((size_t)NN * 5 * sizeof(float4));
    float4*  z15     = (float4*)alloc((size_t)NN * 5 * sizeof(float4));

    curinit_kernel<<<1, 512, 0, stream>>>(cursor);
    sortA_kernel<<<ABLK, 256, 0, stream>>>(src, dst, cursor, tmp);
    bscan_kernel<<<1, 512, 0, stream>>>(cursor, bbase, row_ptr);
    sortB_kernel<<<NBK, 256, 0, stream>>>(tmp, cursor, bbase, dinv, sqd, row_ptr, er_src);
    proj_kernel<<<(NN + 63) / 64, 256, 0, stream>>>((const float4*)feat, W, dinv, z0);

    // one persistent cooperative kernel: 15 prop steps + final, grid-synced
    {
        const float4* a_z0 = z0; float4* a_xa = xa; float4* a_xb = xb;
        float4* a_z13 = z13; float4* a_z14 = z14; float4* a_z15 = z15;
        const int* a_rp = row_ptr; const int* a_es = er_src;
        const float* a_di = dinv; const float* a_sq = sqd;
        const float* a_b = b; float* a_out = out;
        int sb = 0, se = 16;
        void* args[] = { &a_z0, &a_xa, &a_xb, &a_z13, &a_z14, &a_z15,
                         &a_rp, &a_es, &a_di, &a_sq, &a_b, &a_out, &sb, &se };
        hipError_t ce = hipLaunchCooperativeKernel((const void*)spmm_persist,
                                                   dim3(GRID), dim3(BLK), args, 0, stream);
        if (ce != hipSuccess) {
            (void)hipGetLastError();   // clear; fall back to 16 single-step launches
            for (int s = 0; s < 16; ++s)
                spmm_persist<<<GRID, BLK, 0, stream>>>(z0, xa, xb, z13, z14, z15,
                                                       row_ptr, er_src, dinv, sqd,
                                                       b, out, s, s + 1);
        }
    }
}

// Round 8
// 559.682 us; speedup vs baseline: 8.4928x; 5.2176x over previous
//
#include <hip/hip_runtime.h>
#include <hip/hip_fp16.h>

#define NN 100000
#define EE 1200000
#define DD 64
#define CC 40
#define KK 16
#define BSZ 196                          // nodes per sort bucket
#define NBK 512                          // buckets (512*196 = 100352 >= NN)
#define TCAP 3072                        // tmp capacity per bucket (mean 2352, ~15 sigma)
#define EPB 4096                         // edges per phase-A block
#define ABLK ((EE + EPB - 1) / EPB)      // 293

// x layout per state buffer (float4 = 8 halves = 8 channels):
//   P01: [0, 2N)   node n -> {2n, 2n+1};  P23: [2N,4N) same +2N;  P4: [4N,5N) 4N+n
// XCD pinning (block b -> XCD b%8): XCD 0..2 -> planes{0,1} node-thirds,
// 3..5 -> planes{2,3} thirds, 6..7 -> plane{4} halves. Slice/XCD <= 3.2MB.
// Edge-index windows staged into LDS via bulk nt int4 loads. x_out uses NORMAL
// stores (A/B vs r5's nt): the written slice IS next step's gather source on the
// SAME XCD -> dirty-resident L2 handoff (r7 measured 11MB/step fetch with normal).
#define SLT 261                          // slots/XCD: ceil(33334/128)
#define SLT4 196                         // ceil(50000/256)
#define GRID8 (8 * SLT)                  // 2088 blocks of 256 threads
#define CH 4096                          // staged edge-index window (16KB LDS)

typedef int   v4i __attribute__((ext_vector_type(4)));
typedef float v4f __attribute__((ext_vector_type(4)));

__device__ __forceinline__ v4i ntld_i4(const int* p) {
    return __builtin_nontemporal_load((const v4i*)p);
}
__device__ __forceinline__ float4 ntld_f4(const float4* p) {
    v4f v = __builtin_nontemporal_load((const v4f*)p);
    return make_float4(v.x, v.y, v.z, v.w);
}
__device__ __forceinline__ void ntst_f4(float4* p, float4 f) {
    v4f v; v.x = f.x; v.y = f.y; v.z = f.z; v.w = f.w;
    __builtin_nontemporal_store(v, (v4f*)p);
}

// ---------- cursor init ----------
__global__ __launch_bounds__(512) void curinit_kernel(int* __restrict__ cursor) {
    int b = threadIdx.x;
    if (b < NBK) cursor[b] = b * TCAP;
}

// ---------- sort phase A: LDS-bin 4096 edges into 512 buckets ----------
__global__ __launch_bounds__(256) void sortA_kernel(const int* __restrict__ src,
                                                    const int* __restrict__ dst,
                                                    int* __restrict__ cursor,
                                                    int2* __restrict__ tmp) {
    __shared__ int2 stg[EPB];                 // 32KB
    __shared__ int hist[NBK], loff[NBK], lcur[NBK], gbase[NBK];  // 8KB
    int t = threadIdx.x;
    long e0 = (long)blockIdx.x * EPB;
    int n = (int)((EE - e0 < EPB) ? (EE - e0) : EPB);
    for (int j = t; j < NBK; j += 256) hist[j] = 0;
    __syncthreads();
    int d[16], sx[16];
#pragma unroll
    for (int j = 0; j < 16; ++j) {
        int i = t + j * 256;
        if (i < n) {
            d[j] = dst[e0 + i];
            sx[j] = src[e0 + i];
            atomicAdd(&hist[d[j] / BSZ], 1);
        } else d[j] = -1;
    }
    __syncthreads();
    int c0 = hist[2 * t], c1 = hist[2 * t + 1];
    int s2 = c0 + c1;
    __syncthreads();
    loff[t] = s2;
    __syncthreads();
    for (int off = 1; off < 256; off <<= 1) {
        int u = (t >= off) ? loff[t - off] : 0;
        __syncthreads();
        loff[t] += u;
        __syncthreads();
    }
    int excl = loff[t] - s2;
    __syncthreads();
    loff[2 * t] = excl;          loff[2 * t + 1] = excl + c0;
    lcur[2 * t] = excl;          lcur[2 * t + 1] = excl + c0;
    gbase[2 * t]     = atomicAdd(&cursor[2 * t], c0);
    gbase[2 * t + 1] = atomicAdd(&cursor[2 * t + 1], c1);
    __syncthreads();
#pragma unroll
    for (int j = 0; j < 16; ++j) {
        if (d[j] >= 0) {
            int b = d[j] / BSZ;
            int p = atomicAdd(&lcur[b], 1);
            stg[p] = make_int2(d[j], sx[j]);
        }
    }
    __syncthreads();
    for (int i = t; i < n; i += 256) {
        int2 r = stg[i];
        int b = r.x / BSZ;
        int pos = gbase[b] + (i - loff[b]);
        if (pos < (b + 1) * TCAP) tmp[pos] = r;  // overflow guard (never hit)
    }
}

// ---------- bucket-base scan ----------
__global__ __launch_bounds__(512) void bscan_kernel(const int* __restrict__ cursor,
                                                    int* __restrict__ bbase,
                                                    int* __restrict__ row_ptr) {
    __shared__ int sm[512];
    int t = threadIdx.x;
    int v = (t < NBK) ? (cursor[t] - t * TCAP) : 0;
    sm[t] = v;
    __syncthreads();
    for (int off = 1; off < 512; off <<= 1) {
        int u = (t >= off) ? sm[t - off] : 0;
        __syncthreads();
        sm[t] += u;
        __syncthreads();
    }
    if (t < NBK) bbase[t] = sm[t] - v;
    if (t == 511) row_ptr[NN] = sm[511];  // == EE
}

// ---------- sort phase B: counting sort within bucket; emit src-only edges ----------
__global__ __launch_bounds__(256) void sortB_kernel(const int2* __restrict__ tmp,
                                                    const int* __restrict__ cursor,
                                                    const int* __restrict__ bbase,
                                                    float* __restrict__ dinv,
                                                    float* __restrict__ sqd,
                                                    int* __restrict__ row_ptr,
                                                    int* __restrict__ er_src) {
    __shared__ int2 se[TCAP];     // 24KB
    __shared__ int so[TCAP];      // 12KB (src only)
    __shared__ int hist[256], lcur[256];
    int b = blockIdx.x;
    int n0 = b * BSZ;
    if (n0 >= NN) return;
    int n1 = n0 + BSZ; if (n1 > NN) n1 = NN;
    int nb = n1 - n0;
    int t = threadIdx.x;
    int cnt = cursor[b] - b * TCAP;
    int base = bbase[b];
    hist[t] = 0;
    __syncthreads();
    for (int i = t; i < cnt; i += 256) {
        int2 r = tmp[b * TCAP + i];
        se[i] = r;
        atomicAdd(&hist[r.x - n0], 1);
    }
    __syncthreads();
    if (t < nb) {
        float dg = (float)(hist[t] + 1);   // +1 self-loop
        dinv[n0 + t] = rsqrtf(dg);
        sqd[n0 + t]  = sqrtf(dg);
    }
    int v = hist[t];
    lcur[t] = v;
    __syncthreads();
    for (int off = 1; off < 256; off <<= 1) {
        int u = (t >= off) ? lcur[t - off] : 0;
        __syncthreads();
        lcur[t] += u;
        __syncthreads();
    }
    int excl = lcur[t] - v;
    __syncthreads();
    lcur[t] = excl;
    if (t < nb) row_ptr[n0 + t] = base + excl;
    __syncthreads();
    for (int i = t; i < cnt; i += 256) {
        int2 r = se[i];
        int ln = r.x - n0;
        int pos = atomicAdd(&lcur[ln], 1);
        so[pos] = r.y;                    // src only (z-space: weights folded out)
    }
    __syncthreads();
    for (int i = t; i < cnt; i += 256) er_src[base + i] = so[i];  // coalesced
}

// ---------- projection: z0 = dinv * (feat @ W^T), stored in P-layout ----------
__global__ __launch_bounds__(256) void proj_kernel(const float4* __restrict__ feat4,
                                                   const float* __restrict__ W,
                                                   const float* __restrict__ dinv,
                                                   float4* __restrict__ z0) {
    __shared__ float smW[CC * 68];   // 10.9KB
    __shared__ float smF[64 * 68];   // 17.4KB
    __shared__ float smO[64 * 42];   // 10.8KB
    int t = threadIdx.x;
    for (int j = t; j < CC * 16; j += 256) {
        int c = j >> 4, q = j & 15;
        *(float4*)(smW + c * 68 + q * 4) = ((const float4*)W)[j];
    }
    int n0 = blockIdx.x * 64;
    for (int j = t; j < 64 * 16; j += 256) {
        int r = j >> 4, q = j & 15;
        if (n0 + r < NN)
            *(float4*)(smF + r * 68 + q * 4) = feat4[(size_t)(n0 + r) * 16 + q];
    }
    __syncthreads();
    int ln = t >> 2, c0 = (t & 3) * 10;
    int node = n0 + ln;
    float acc[10];
#pragma unroll
    for (int c = 0; c < 10; ++c) acc[c] = 0.f;
    if (node < NN) {
#pragma unroll
        for (int db = 0; db < 16; ++db) {
            float4 fv = *(const float4*)(smF + ln * 68 + db * 4);
#pragma unroll
            for (int c = 0; c < 10; ++c) {
                float4 wv = *(const float4*)(smW + (c0 + c) * 68 + db * 4);
                acc[c] = fmaf(fv.x, wv.x, acc[c]);
                acc[c] = fmaf(fv.y, wv.y, acc[c]);
                acc[c] = fmaf(fv.z, wv.z, acc[c]);
                acc[c] = fmaf(fv.w, wv.w, acc[c]);
            }
        }
    }
#pragma unroll
    for (int c = 0; c < 10; ++c) smO[ln * 42 + c0 + c] = acc[c];
    __syncthreads();
    for (int j = t; j < 64 * 5; j += 256) {
        int r = j & 63, q = j >> 6;
        int g = n0 + r;
        if (g < NN) {
            float dv = dinv[g];
            const float* s = smO + r * 42 + q * 8;
            float4 ov;
            __half2* op = (__half2*)&ov;
            op[0] = __floats2half2_rn(dv * s[0], dv * s[1]);
            op[1] = __floats2half2_rn(dv * s[2], dv * s[3]);
            op[2] = __floats2half2_rn(dv * s[4], dv * s[5]);
            op[3] = __floats2half2_rn(dv * s[6], dv * s[7]);
            size_t idx = (q < 2) ? ((size_t)g * 2 + q)
                       : (q < 4) ? ((size_t)2 * NN + (size_t)g * 2 + (q - 2))
                                 : ((size_t)4 * NN + g);
            z0[idx] = ov;
        }
    }
}

// decode float4-of-8-halves into 8 floats
#define DEC8(V, F0, F1, F2, F3)                                             \
    const __half2* hp_##F0 = (const __half2*)&(V);                          \
    float2 F0 = __half22float2(hp_##F0[0]), F1 = __half22float2(hp_##F0[1]);\
    float2 F2 = __half22float2(hp_##F0[2]), F3 = __half22float2(hp_##F0[3]);

#define ACC8U(V)                                                            \
    {                                                                       \
        DEC8(V, f0, f1, f2, f3)                                             \
        a0 += f0.x; a1 += f0.y; a2 += f1.x; a3 += f1.y;                     \
        a4 += f2.x; a5 += f2.y; a6 += f3.x; a7 += f3.y;                     \
    }

// gather loop over the LDS-staged edge window [W0,W1), my row clipped to it.
#define GATHER_WINDOW(XP, STR, PL)                                          \
    {                                                                       \
        int lo = (beg > W0) ? beg : W0;                                     \
        int hi = (end < W1) ? end : W1;                                     \
        int e = lo;                                                         \
        for (; e + 8 <= hi; e += 8) {                                       \
            int s0 = sidx[e - A0 + 0], s1 = sidx[e - A0 + 1];               \
            int s2 = sidx[e - A0 + 2], s3 = sidx[e - A0 + 3];               \
            int s4 = sidx[e - A0 + 4], s5 = sidx[e - A0 + 5];               \
            int s6 = sidx[e - A0 + 6], s7 = sidx[e - A0 + 7];               \
            float4 v0 = (XP)[s0 * (STR) + (PL)];                            \
            float4 v1 = (XP)[s1 * (STR) + (PL)];                            \
            float4 v2 = (XP)[s2 * (STR) + (PL)];                            \
            float4 v3 = (XP)[s3 * (STR) + (PL)];                            \
            float4 v4 = (XP)[s4 * (STR) + (PL)];                            \
            float4 v5 = (XP)[s5 * (STR) + (PL)];                            \
            float4 v6 = (XP)[s6 * (STR) + (PL)];                            \
            float4 v7 = (XP)[s7 * (STR) + (PL)];                            \
            ACC8U(v0); ACC8U(v1); ACC8U(v2); ACC8U(v3);                     \
            ACC8U(v4); ACC8U(v5); ACC8U(v6); ACC8U(v7);                     \
        }                                                                   \
        if (e + 4 <= hi) {                                                  \
            int s0 = sidx[e - A0 + 0], s1 = sidx[e - A0 + 1];               \
            int s2 = sidx[e - A0 + 2], s3 = sidx[e - A0 + 3];               \
            float4 v0 = (XP)[s0 * (STR) + (PL)];                            \
            float4 v1 = (XP)[s1 * (STR) + (PL)];                            \
            float4 v2 = (XP)[s2 * (STR) + (PL)];                            \
            float4 v3 = (XP)[s3 * (STR) + (PL)];                            \
            ACC8U(v0); ACC8U(v1); ACC8U(v2); ACC8U(v3);                     \
            e += 4;                                                         \
        }                                                                   \
        for (; e < hi; ++e) {                                               \
            int s = sidx[e - A0];                                           \
            float4 v = (XP)[s * (STR) + (PL)];                              \
            ACC8U(v);                                                       \
        }                                                                   \
    }

// stage es[W0..W1) into LDS with bulk nt int4 loads (no L1/L2 allocation)
#define STAGE_WINDOW                                                        \
    int W1 = (W0 + CH < blkE) ? (W0 + CH) : blkE;                           \
    int A0 = W0 & ~3;                                                       \
    __syncthreads();                                                        \
    for (int i = A0 + (int)threadIdx.x * 4; i < W1; i += 1024) {            \
        *(v4i*)(sidx + (i - A0)) = ntld_i4(es + i);                         \
    }                                                                       \
    __syncthreads();

// ---------- SpMM propagate body: z_out[d] = dinv[d]^2 * (z[d] + sum z[src]) ----------
template <int STR>
__device__ __forceinline__ void prop_body(
    int* sidx, int n0, int n1, int g, bool act, int pl, size_t off,
    const float4* __restrict__ x, float4* __restrict__ x_out,
    const int* __restrict__ row_ptr, const int* __restrict__ es,
    const float* __restrict__ dinv) {
    const float4* xp = x + off;
    int beg = 0, end = 0, sb = 0;
    float w2 = 0.f;
    float a0 = 0, a1 = 0, a2 = 0, a3 = 0, a4 = 0, a5 = 0, a6 = 0, a7 = 0;
    if (act) {
        beg = row_ptr[g]; end = row_ptr[g + 1];
        float di = dinv[g];
        w2 = di * di;
        sb = g * STR + pl;
        float4 sv = xp[sb];
        DEC8(sv, f0, f1, f2, f3)
        a0 = f0.x; a1 = f0.y; a2 = f1.x; a3 = f1.y;
        a4 = f2.x; a5 = f2.y; a6 = f3.x; a7 = f3.y;
    }
    int blkB = row_ptr[n0], blkE = row_ptr[n1];
    for (int W0 = blkB; W0 < blkE; W0 += CH) {
        STAGE_WINDOW
        if (act) GATHER_WINDOW(xp, STR, pl)
    }
    if (act) {
        float4 ov;
        __half2* op = (__half2*)&ov;
        op[0] = __floats2half2_rn(w2 * a0, w2 * a1);
        op[1] = __floats2half2_rn(w2 * a2, w2 * a3);
        op[2] = __floats2half2_rn(w2 * a4, w2 * a5);
        op[3] = __floats2half2_rn(w2 * a6, w2 * a7);
        x_out[off + sb] = ov;   // NORMAL store: dirty-resident L2 handoff to next step
    }
}

__global__ __launch_bounds__(256) void spmm_prop(
    const float4* __restrict__ x, float4* __restrict__ x_out,
    const int* __restrict__ row_ptr, const int* __restrict__ es,
    const float* __restrict__ dinv) {
    __shared__ __align__(16) int sidx[CH + 8];
    int xcd = blockIdx.x & 7;
    int slot = blockIdx.x >> 3;
    int t = threadIdx.x;
    if (xcd < 6) {
        int part = (xcd < 3) ? xcd : xcd - 3;
        int grp  = (xcd < 3) ? 0 : 1;
        int b0 = (part == 0) ? 0 : ((part == 1) ? 33334 : 66667);
        int b1 = (part == 0) ? 33334 : ((part == 1) ? 66667 : 100000);
        int n0 = b0 + slot * 128;
        int n1 = (n0 + 128 < b1) ? (n0 + 128) : b1;
        int g = n0 + (t >> 1);
        prop_body<2>(sidx, n0, n1, g, g < n1, t & 1, (size_t)grp * 2 * NN,
                     x, x_out, row_ptr, es, dinv);
    } else {
        if (slot >= SLT4) return;
        int b0 = (xcd - 6) * 50000;
        int lim = b0 + 50000;
        int n0 = b0 + slot * 256;
        int n1 = (n0 + 256 < lim) ? (n0 + 256) : lim;
        int g = n0 + t;
        prop_body<1>(sidx, n0, n1, g, g < n1, 0, (size_t)4 * NN,
                     x, x_out, row_ptr, es, dinv);
    }
}

// ---------- final: acc = sum z15 (incl self); out = C16*dinv*acc
//            + sqd*(C15*z15 + C14*z14 + C13*z13 + FC*z0) + bias ----------
template <int STR>
__device__ __forceinline__ void final_body(
    int* sidx, int n0, int n1, int g, bool act, int pl, int p, size_t off,
    const float4* __restrict__ x15, const float4* __restrict__ x13p,
    const float4* __restrict__ x14p, const float4* __restrict__ z0p,
    const float* __restrict__ bias,
    const int* __restrict__ row_ptr, const int* __restrict__ es,
    const float* __restrict__ dinv, const float* __restrict__ sqd,
    float* __restrict__ outp) {
    const float4* xp = x15 + off;
    int beg = 0, end = 0, sb = 0;
    float di = 0.f, sq = 0.f;
    float s0 = 0, s1 = 0, s2 = 0, s3 = 0, s4 = 0, s5 = 0, s6 = 0, s7 = 0;
    float a0 = 0, a1 = 0, a2 = 0, a3 = 0, a4 = 0, a5 = 0, a6 = 0, a7 = 0;
    if (act) {
        beg = row_ptr[g]; end = row_ptr[g + 1];
        di = dinv[g];
        sq = sqd[g];
        sb = g * STR + pl;
        float4 sv = xp[sb];
        DEC8(sv, f0, f1, f2, f3)
        s0 = f0.x; s1 = f0.y; s2 = f1.x; s3 = f1.y;
        s4 = f2.x; s5 = f2.y; s6 = f3.x; s7 = f3.y;
        a0 = s0; a1 = s1; a2 = s2; a3 = s3;
        a4 = s4; a5 = s5; a6 = s6; a7 = s7;
    }
    int blkB = row_ptr[n0], blkE = row_ptr[n1];
    for (int W0 = blkB; W0 < blkE; W0 += CH) {
        STAGE_WINDOW
        if (act) GATHER_WINDOW(xp, STR, pl)
    }
    if (!act) return;
    size_t gi = off + sb;
    const float C16 = 0.95f / 16.0f;
    const float C15 = 0.95f / 256.0f;
    const float C14 = 0.95f / 4096.0f;
    const float C13 = 0.95f / 65536.0f;
    const float FC  = 0.05f / 15.0f;
    float t0 = C15 * s0, t1 = C15 * s1, t2 = C15 * s2, t3 = C15 * s3;
    float t4 = C15 * s4, t5 = C15 * s5, t6 = C15 * s6, t7 = C15 * s7;
#define ADD8T(P, CF)                                                        \
    {                                                                       \
        float4 v = ntld_f4((P) + gi);                                       \
        DEC8(v, f0, f1, f2, f3)                                             \
        t0 = fmaf((CF), f0.x, t0); t1 = fmaf((CF), f0.y, t1);               \
        t2 = fmaf((CF), f1.x, t2); t3 = fmaf((CF), f1.y, t3);               \
        t4 = fmaf((CF), f2.x, t4); t5 = fmaf((CF), f2.y, t5);               \
        t6 = fmaf((CF), f3.x, t6); t7 = fmaf((CF), f3.y, t7);               \
    }
    ADD8T(x14p, C14)
    ADD8T(x13p, C13)
    ADD8T(z0p, FC)
#undef ADD8T
    float cd = C16 * di;
    float o0 = fmaf(sq, t0, cd * a0), o1 = fmaf(sq, t1, cd * a1);
    float o2 = fmaf(sq, t2, cd * a2), o3 = fmaf(sq, t3, cd * a3);
    float o4 = fmaf(sq, t4, cd * a4), o5 = fmaf(sq, t5, cd * a5);
    float o6 = fmaf(sq, t6, cd * a6), o7 = fmaf(sq, t7, cd * a7);
    const float4* b4 = (const float4*)(bias + p * 8);
    float4 bb0 = b4[0], bb1 = b4[1];
    float4* op = (float4*)(outp + (size_t)g * CC + p * 8);
    ntst_f4(op,     make_float4(o0 + bb0.x, o1 + bb0.y, o2 + bb0.z, o3 + bb0.w));
    ntst_f4(op + 1, make_float4(o4 + bb1.x, o5 + bb1.y, o6 + bb1.z, o7 + bb1.w));
}

__global__ __launch_bounds__(256) void spmm_final(
    const float4* __restrict__ x15, const float4* __restrict__ x13p,
    const float4* __restrict__ x14p, const float4* __restrict__ z0p,
    const float* __restrict__ bias,
    const int* __restrict__ row_ptr, const int* __restrict__ es,
    const float* __restrict__ dinv, const float* __restrict__ sqd,
    float* __restrict__ outp) {
    __shared__ __align__(16) int sidx[CH + 8];
    int xcd = blockIdx.x & 7;
    int slot = blockIdx.x >> 3;
    int t = threadIdx.x;
    if (xcd < 6) {
        int part = (xcd < 3) ? xcd : xcd - 3;
        int grp  = (xcd < 3) ? 0 : 1;
        int b0 = (part == 0) ? 0 : ((part == 1) ? 33334 : 66667);
        int b1 = (part == 0) ? 33334 : ((part == 1) ? 66667 : 100000);
        int n0 = b0 + slot * 128;
        int n1 = (n0 + 128 < b1) ? (n0 + 128) : b1;
        int g = n0 + (t >> 1);
        int pl = t & 1;
        final_body<2>(sidx, n0, n1, g, g < n1, pl, grp * 2 + pl, (size_t)grp * 2 * NN,
                      x15, x13p, x14p, z0p, bias, row_ptr, es, dinv, sqd, outp);
    } else {
        if (slot >= SLT4) return;
        int b0 = (xcd - 6) * 50000;
        int lim = b0 + 50000;
        int n0 = b0 + slot * 256;
        int n1 = (n0 + 256 < lim) ? (n0 + 256) : lim;
        int g = n0 + t;
        final_body<1>(sidx, n0, n1, g, g < n1, 0, 4, (size_t)4 * NN,
                      x15, x13p, x14p, z0p, bias, row_ptr, es, dinv, sqd, outp);
    }
}

extern "C" void kernel_launch(void* const* d_in, const int* in_sizes, int n_in,
                              void* d_out, int out_size, void* d_ws, size_t ws_size,
                              hipStream_t stream) {
    const float* feat = (const float*)d_in[0];
    const float* W    = (const float*)d_in[1];
    const float* b    = (const float*)d_in[2];
    const int*   src  = (const int*)d_in[3];
    const int*   dst  = (const int*)d_in[4];
    float* out = (float*)d_out;

    char* p = (char*)d_ws;
    auto alloc = [&](size_t bytes) {
        char* r = p;
        p += (bytes + 255) & ~(size_t)255;
        return r;
    };
    float*   dinv    = (float*)alloc((size_t)NN * sizeof(float));
    float*   sqd     = (float*)alloc((size_t)NN * sizeof(float));
    int*     row_ptr = (int*)alloc((size_t)(NN + 1) * sizeof(int));
    int*     cursor  = (int*)alloc((size_t)NBK * sizeof(int));
    int*     bbase   = (int*)alloc((size_t)NBK * sizeof(int));
    int2*    tmp     = (int2*)alloc((size_t)NBK * TCAP * sizeof(int2));  // 12.6MB
    int*     er_src  = (int*)alloc((size_t)EE * sizeof(int) + 64);       // 4.8MB (+pad for int4 tail)
    float4*  z0      = (float4*)alloc((size_t)NN * 5 * sizeof(float4));  // 8MB
    float4*  xa      = (float4*)alloc((size_t)NN * 5 * sizeof(float4));  // 8MB
    float4*  xb      = (float4*)alloc((size_t)NN * 5 * sizeof(float4));  // 8MB
    float4*  z13     = (float4*)alloc((size_t)NN * 5 * sizeof(float4));  // 8MB
    float4*  z14     = (float4*)alloc((size_t)NN * 5 * sizeof(float4));  // 8MB
    float4*  z15     = (float4*)alloc((size_t)NN * 5 * sizeof(float4));  // 8MB

    curinit_kernel<<<1, 512, 0, stream>>>(cursor);
    sortA_kernel<<<ABLK, 256, 0, stream>>>(src, dst, cursor, tmp);
    bscan_kernel<<<1, 512, 0, stream>>>(cursor, bbase, row_ptr);
    sortB_kernel<<<NBK, 256, 0, stream>>>(tmp, cursor, bbase, dinv, sqd, row_ptr, er_src);
    proj_kernel<<<(NN + 63) / 64, 256, 0, stream>>>((const float4*)feat, W, dinv, z0);

    // z1..z12: ping-pong xa/xb
    const float4* xs = z0;
    for (int j = 0; j < 12; ++j) {
        float4* xd = (j & 1) ? xb : xa;
        spmm_prop<<<GRID8, 256, 0, stream>>>(xs, xd, row_ptr, er_src, dinv);
        xs = xd;
    }
    // z13, z14, z15 into preserved buffers
    spmm_prop<<<GRID8, 256, 0, stream>>>(xs, z13, row_ptr, er_src, dinv);
    spmm_prop<<<GRID8, 256, 0, stream>>>(z13, z14, row_ptr, er_src, dinv);
    spmm_prop<<<GRID8, 256, 0, stream>>>(z14, z15, row_ptr, er_src, dinv);
    // final combine
    spmm_final<<<GRID8, 256, 0, stream>>>(z15, z13, z14, z0, b, row_ptr,
                                          er_src, dinv, sqd, out);
}

// Round 9
// 519.752 us; speedup vs baseline: 9.1453x; 1.0768x over previous
//
#include <hip/hip_runtime.h>
#include <hip/hip_fp16.h>

#define NN 100000
#define EE 1200000
#define DD 64
#define CC 40
#define BSZ 196                          // nodes per sort bucket
#define NBK 512                          // buckets (512*196 = 100352 >= NN)
#define TCAP 3072                        // tmp capacity per bucket (mean 2352, ~15 sigma)
#define EPB 4096                         // edges per phase-A block
#define ABLK ((EE + EPB - 1) / EPB)      // 293

// x layout per state buffer (float4 = 8 halves = 8 channels):
//   Region A [0,4N):  node n -> float4 n*4+q, q=0..3  (channels 0..31, 64B/node = 1 line)
//   Region B [4N,5N): node n -> 4N+n                  (channels 32..39, 16B/node)
// Request-balanced XCD mapping (block b -> XCD b%8):
//   XCD 0..3: region A, dest quarters, 4 lanes/node -> the quad's 4x16B loads
//             coalesce to ONE line-request per edge covering 32 channels.
//   XCD 4..7: region B, dest quarters, 1 lane/node.
// => 300K line-requests/XCD/step balanced (was 400/400/600K skewed) — the
// measured ~27us/step tracked the 600K max (L2 request-service bound).
// G1 slice 6.4MB > 4MB L2 (~60% hit, L3 absorbs misses) — accepted trade.
#define SL1 391                          // ceil(25000/64) G1 slots/XCD
#define SL2 98                           // ceil(25000/256) G2 slots/XCD
#define GRID8 (8 * SL1)                  // 3128 blocks of 256 threads
#define CH 4096                          // staged edge-index window (16KB LDS)

typedef int   v4i __attribute__((ext_vector_type(4)));
typedef float v4f __attribute__((ext_vector_type(4)));

__device__ __forceinline__ v4i ntld_i4(const int* p) {
    return __builtin_nontemporal_load((const v4i*)p);
}
__device__ __forceinline__ float4 ntld_f4(const float4* p) {
    v4f v = __builtin_nontemporal_load((const v4f*)p);
    return make_float4(v.x, v.y, v.z, v.w);
}
__device__ __forceinline__ void ntst_f4(float4* p, float4 f) {
    v4f v; v.x = f.x; v.y = f.y; v.z = f.z; v.w = f.w;
    __builtin_nontemporal_store(v, (v4f*)p);
}

// ---------- cursor init ----------
__global__ __launch_bounds__(512) void curinit_kernel(int* __restrict__ cursor) {
    int b = threadIdx.x;
    if (b < NBK) cursor[b] = b * TCAP;
}

// ---------- sort phase A: LDS-bin 4096 edges into 512 buckets ----------
__global__ __launch_bounds__(256) void sortA_kernel(const int* __restrict__ src,
                                                    const int* __restrict__ dst,
                                                    int* __restrict__ cursor,
                                                    int2* __restrict__ tmp) {
    __shared__ int2 stg[EPB];                 // 32KB
    __shared__ int hist[NBK], loff[NBK], lcur[NBK], gbase[NBK];  // 8KB
    int t = threadIdx.x;
    long e0 = (long)blockIdx.x * EPB;
    int n = (int)((EE - e0 < EPB) ? (EE - e0) : EPB);
    for (int j = t; j < NBK; j += 256) hist[j] = 0;
    __syncthreads();
    int d[16], sx[16];
#pragma unroll
    for (int j = 0; j < 16; ++j) {
        int i = t + j * 256;
        if (i < n) {
            d[j] = dst[e0 + i];
            sx[j] = src[e0 + i];
            atomicAdd(&hist[d[j] / BSZ], 1);
        } else d[j] = -1;
    }
    __syncthreads();
    int c0 = hist[2 * t], c1 = hist[2 * t + 1];
    int s2 = c0 + c1;
    __syncthreads();
    loff[t] = s2;
    __syncthreads();
    for (int off = 1; off < 256; off <<= 1) {
        int u = (t >= off) ? loff[t - off] : 0;
        __syncthreads();
        loff[t] += u;
        __syncthreads();
    }
    int excl = loff[t] - s2;
    __syncthreads();
    loff[2 * t] = excl;          loff[2 * t + 1] = excl + c0;
    lcur[2 * t] = excl;          lcur[2 * t + 1] = excl + c0;
    gbase[2 * t]     = atomicAdd(&cursor[2 * t], c0);
    gbase[2 * t + 1] = atomicAdd(&cursor[2 * t + 1], c1);
    __syncthreads();
#pragma unroll
    for (int j = 0; j < 16; ++j) {
        if (d[j] >= 0) {
            int b = d[j] / BSZ;
            int p = atomicAdd(&lcur[b], 1);
            stg[p] = make_int2(d[j], sx[j]);
        }
    }
    __syncthreads();
    for (int i = t; i < n; i += 256) {
        int2 r = stg[i];
        int b = r.x / BSZ;
        int pos = gbase[b] + (i - loff[b]);
        if (pos < (b + 1) * TCAP) tmp[pos] = r;  // overflow guard (never hit)
    }
}

// ---------- bucket-base scan ----------
__global__ __launch_bounds__(512) void bscan_kernel(const int* __restrict__ cursor,
                                                    int* __restrict__ bbase,
                                                    int* __restrict__ row_ptr) {
    __shared__ int sm[512];
    int t = threadIdx.x;
    int v = (t < NBK) ? (cursor[t] - t * TCAP) : 0;
    sm[t] = v;
    __syncthreads();
    for (int off = 1; off < 512; off <<= 1) {
        int u = (t >= off) ? sm[t - off] : 0;
        __syncthreads();
        sm[t] += u;
        __syncthreads();
    }
    if (t < NBK) bbase[t] = sm[t] - v;
    if (t == 511) row_ptr[NN] = sm[511];  // == EE
}

// ---------- sort phase B: counting sort within bucket; emit src-only edges ----------
__global__ __launch_bounds__(256) void sortB_kernel(const int2* __restrict__ tmp,
                                                    const int* __restrict__ cursor,
                                                    const int* __restrict__ bbase,
                                                    float* __restrict__ dinv,
                                                    float* __restrict__ sqd,
                                                    int* __restrict__ row_ptr,
                                                    int* __restrict__ er_src) {
    __shared__ int2 se[TCAP];     // 24KB
    __shared__ int so[TCAP];      // 12KB (src only)
    __shared__ int hist[256], lcur[256];
    int b = blockIdx.x;
    int n0 = b * BSZ;
    if (n0 >= NN) return;
    int n1 = n0 + BSZ; if (n1 > NN) n1 = NN;
    int nb = n1 - n0;
    int t = threadIdx.x;
    int cnt = cursor[b] - b * TCAP;
    int base = bbase[b];
    hist[t] = 0;
    __syncthreads();
    for (int i = t; i < cnt; i += 256) {
        int2 r = tmp[b * TCAP + i];
        se[i] = r;
        atomicAdd(&hist[r.x - n0], 1);
    }
    __syncthreads();
    if (t < nb) {
        float dg = (float)(hist[t] + 1);   // +1 self-loop
        dinv[n0 + t] = rsqrtf(dg);
        sqd[n0 + t]  = sqrtf(dg);
    }
    int v = hist[t];
    lcur[t] = v;
    __syncthreads();
    for (int off = 1; off < 256; off <<= 1) {
        int u = (t >= off) ? lcur[t - off] : 0;
        __syncthreads();
        lcur[t] += u;
        __syncthreads();
    }
    int excl = lcur[t] - v;
    __syncthreads();
    lcur[t] = excl;
    if (t < nb) row_ptr[n0 + t] = base + excl;
    __syncthreads();
    for (int i = t; i < cnt; i += 256) {
        int2 r = se[i];
        int ln = r.x - n0;
        int pos = atomicAdd(&lcur[ln], 1);
        so[pos] = r.y;                    // src only (z-space: weights folded out)
    }
    __syncthreads();
    for (int i = t; i < cnt; i += 256) er_src[base + i] = so[i];  // coalesced
}

// ---------- projection: z0 = dinv * (feat @ W^T), stored in A/B layout ----------
__global__ __launch_bounds__(256) void proj_kernel(const float4* __restrict__ feat4,
                                                   const float* __restrict__ W,
                                                   const float* __restrict__ dinv,
                                                   float4* __restrict__ z0) {
    __shared__ float smW[CC * 68];   // 10.9KB
    __shared__ float smF[64 * 68];   // 17.4KB
    __shared__ float smO[64 * 42];   // 10.8KB
    int t = threadIdx.x;
    for (int j = t; j < CC * 16; j += 256) {
        int c = j >> 4, q = j & 15;
        *(float4*)(smW + c * 68 + q * 4) = ((const float4*)W)[j];
    }
    int n0 = blockIdx.x * 64;
    for (int j = t; j < 64 * 16; j += 256) {
        int r = j >> 4, q = j & 15;
        if (n0 + r < NN)
            *(float4*)(smF + r * 68 + q * 4) = feat4[(size_t)(n0 + r) * 16 + q];
    }
    __syncthreads();
    int ln = t >> 2, c0 = (t & 3) * 10;
    int node = n0 + ln;
    float acc[10];
#pragma unroll
    for (int c = 0; c < 10; ++c) acc[c] = 0.f;
    if (node < NN) {
#pragma unroll
        for (int db = 0; db < 16; ++db) {
            float4 fv = *(const float4*)(smF + ln * 68 + db * 4);
#pragma unroll
            for (int c = 0; c < 10; ++c) {
                float4 wv = *(const float4*)(smW + (c0 + c) * 68 + db * 4);
                acc[c] = fmaf(fv.x, wv.x, acc[c]);
                acc[c] = fmaf(fv.y, wv.y, acc[c]);
                acc[c] = fmaf(fv.z, wv.z, acc[c]);
                acc[c] = fmaf(fv.w, wv.w, acc[c]);
            }
        }
    }
#pragma unroll
    for (int c = 0; c < 10; ++c) smO[ln * 42 + c0 + c] = acc[c];
    __syncthreads();
    // region A: j in [0,256): r=j>>2, q=j&3 -> idx g*4+q (coalesced)
    {
        int r = t >> 2, q = t & 3;
        int g = n0 + r;
        if (g < NN) {
            float dv = dinv[g];
            const float* s = smO + r * 42 + q * 8;
            float4 ov;
            __half2* op = (__half2*)&ov;
            op[0] = __floats2half2_rn(dv * s[0], dv * s[1]);
            op[1] = __floats2half2_rn(dv * s[2], dv * s[3]);
            op[2] = __floats2half2_rn(dv * s[4], dv * s[5]);
            op[3] = __floats2half2_rn(dv * s[6], dv * s[7]);
            z0[(size_t)g * 4 + q] = ov;
        }
    }
    // region B: t in [0,64): channels 32..39 -> idx 4N+g
    if (t < 64) {
        int g = n0 + t;
        if (g < NN) {
            float dv = dinv[g];
            const float* s = smO + t * 42 + 32;
            float4 ov;
            __half2* op = (__half2*)&ov;
            op[0] = __floats2half2_rn(dv * s[0], dv * s[1]);
            op[1] = __floats2half2_rn(dv * s[2], dv * s[3]);
            op[2] = __floats2half2_rn(dv * s[4], dv * s[5]);
            op[3] = __floats2half2_rn(dv * s[6], dv * s[7]);
            z0[(size_t)4 * NN + g] = ov;
        }
    }
}

// decode float4-of-8-halves into 8 floats
#define DEC8(V, F0, F1, F2, F3)                                             \
    const __half2* hp_##F0 = (const __half2*)&(V);                          \
    float2 F0 = __half22float2(hp_##F0[0]), F1 = __half22float2(hp_##F0[1]);\
    float2 F2 = __half22float2(hp_##F0[2]), F3 = __half22float2(hp_##F0[3]);

#define ACC8U(V)                                                            \
    {                                                                       \
        DEC8(V, f0, f1, f2, f3)                                             \
        a0 += f0.x; a1 += f0.y; a2 += f1.x; a3 += f1.y;                     \
        a4 += f2.x; a5 += f2.y; a6 += f3.x; a7 += f3.y;                     \
    }

// gather loop over the LDS-staged edge window [W0,W1), my row clipped to it.
#define GATHER_WINDOW(XP, STR, PL)                                          \
    {                                                                       \
        int lo = (beg > W0) ? beg : W0;                                     \
        int hi = (end < W1) ? end : W1;                                     \
        int e = lo;                                                         \
        for (; e + 8 <= hi; e += 8) {                                       \
            int s0 = sidx[e - A0 + 0], s1 = sidx[e - A0 + 1];               \
            int s2 = sidx[e - A0 + 2], s3 = sidx[e - A0 + 3];               \
            int s4 = sidx[e - A0 + 4], s5 = sidx[e - A0 + 5];               \
            int s6 = sidx[e - A0 + 6], s7 = sidx[e - A0 + 7];               \
            float4 v0 = (XP)[s0 * (STR) + (PL)];                            \
            float4 v1 = (XP)[s1 * (STR) + (PL)];                            \
            float4 v2 = (XP)[s2 * (STR) + (PL)];                            \
            float4 v3 = (XP)[s3 * (STR) + (PL)];                            \
            float4 v4 = (XP)[s4 * (STR) + (PL)];                            \
            float4 v5 = (XP)[s5 * (STR) + (PL)];                            \
            float4 v6 = (XP)[s6 * (STR) + (PL)];                            \
            float4 v7 = (XP)[s7 * (STR) + (PL)];                            \
            ACC8U(v0); ACC8U(v1); ACC8U(v2); ACC8U(v3);                     \
            ACC8U(v4); ACC8U(v5); ACC8U(v6); ACC8U(v7);                     \
        }                                                                   \
        if (e + 4 <= hi) {                                                  \
            int s0 = sidx[e - A0 + 0], s1 = sidx[e - A0 + 1];               \
            int s2 = sidx[e - A0 + 2], s3 = sidx[e - A0 + 3];               \
            float4 v0 = (XP)[s0 * (STR) + (PL)];                            \
            float4 v1 = (XP)[s1 * (STR) + (PL)];                            \
            float4 v2 = (XP)[s2 * (STR) + (PL)];                            \
            float4 v3 = (XP)[s3 * (STR) + (PL)];                            \
            ACC8U(v0); ACC8U(v1); ACC8U(v2); ACC8U(v3);                     \
            e += 4;                                                         \
        }                                                                   \
        for (; e < hi; ++e) {                                               \
            int s = sidx[e - A0];                                           \
            float4 v = (XP)[s * (STR) + (PL)];                              \
            ACC8U(v);                                                       \
        }                                                                   \
    }

// stage es[W0..W1) into LDS with bulk nt int4 loads (no L1/L2 allocation)
#define STAGE_WINDOW                                                        \
    int W1 = (W0 + CH < blkE) ? (W0 + CH) : blkE;                           \
    int A0 = W0 & ~3;                                                       \
    __syncthreads();                                                        \
    for (int i = A0 + (int)threadIdx.x * 4; i < W1; i += 1024) {            \
        *(v4i*)(sidx + (i - A0)) = ntld_i4(es + i);                         \
    }                                                                       \
    __syncthreads();

// ---------- SpMM propagate body: z_out[d] = dinv[d]^2 * (z[d] + sum z[src]) ----------
template <int STR>
__device__ __forceinline__ void prop_body(
    int* sidx, int n0, int n1, int g, bool act, int pl, size_t off,
    const float4* __restrict__ x, float4* __restrict__ x_out,
    const int* __restrict__ row_ptr, const int* __restrict__ es,
    const float* __restrict__ dinv) {
    const float4* xp = x + off;
    int beg = 0, end = 0, sb = 0;
    float w2 = 0.f;
    float a0 = 0, a1 = 0, a2 = 0, a3 = 0, a4 = 0, a5 = 0, a6 = 0, a7 = 0;
    if (act) {
        beg = row_ptr[g]; end = row_ptr[g + 1];
        float di = dinv[g];
        w2 = di * di;
        sb = g * STR + pl;
        float4 sv = xp[sb];
        DEC8(sv, f0, f1, f2, f3)
        a0 = f0.x; a1 = f0.y; a2 = f1.x; a3 = f1.y;
        a4 = f2.x; a5 = f2.y; a6 = f3.x; a7 = f3.y;
    }
    int blkB = row_ptr[n0], blkE = row_ptr[n1];
    for (int W0 = blkB; W0 < blkE; W0 += CH) {
        STAGE_WINDOW
        if (act) GATHER_WINDOW(xp, STR, pl)
    }
    if (act) {
        float4 ov;
        __half2* op = (__half2*)&ov;
        op[0] = __floats2half2_rn(w2 * a0, w2 * a1);
        op[1] = __floats2half2_rn(w2 * a2, w2 * a3);
        op[2] = __floats2half2_rn(w2 * a4, w2 * a5);
        op[3] = __floats2half2_rn(w2 * a6, w2 * a7);
        ntst_f4(x_out + off + sb, ov);   // nt: keep gather slice unpolluted (r5 winner)
    }
}

__global__ __launch_bounds__(256) void spmm_prop(
    const float4* __restrict__ x, float4* __restrict__ x_out,
    const int* __restrict__ row_ptr, const int* __restrict__ es,
    const float* __restrict__ dinv) {
    __shared__ __align__(16) int sidx[CH + 8];
    int xcd = blockIdx.x & 7;
    int slot = blockIdx.x >> 3;
    int t = threadIdx.x;
    if (xcd < 4) {
        int q0 = xcd * 25000;
        int n0 = q0 + slot * 64;
        int n1 = (n0 + 64 < q0 + 25000) ? (n0 + 64) : (q0 + 25000);
        int g = n0 + (t >> 2);
        prop_body<4>(sidx, n0, n1, g, g < n1, t & 3, 0,
                     x, x_out, row_ptr, es, dinv);
    } else {
        if (slot >= SL2) return;
        int q0 = (xcd - 4) * 25000;
        int n0 = q0 + slot * 256;
        int n1 = (n0 + 256 < q0 + 25000) ? (n0 + 256) : (q0 + 25000);
        int g = n0 + t;
        prop_body<1>(sidx, n0, n1, g, g < n1, 0, (size_t)4 * NN,
                     x, x_out, row_ptr, es, dinv);
    }
}

// ---------- final: acc = sum z15 (incl self); out = C16*dinv*acc
//            + sqd*(C15*z15 + C14*z14 + C13*z13 + FC*z0) + bias ----------
template <int STR>
__device__ __forceinline__ void final_body(
    int* sidx, int n0, int n1, int g, bool act, int pl, int p, size_t off,
    const float4* __restrict__ x15, const float4* __restrict__ x13p,
    const float4* __restrict__ x14p, const float4* __restrict__ z0p,
    const float* __restrict__ bias,
    const int* __restrict__ row_ptr, const int* __restrict__ es,
    const float* __restrict__ dinv, const float* __restrict__ sqd,
    float* __restrict__ outp) {
    const float4* xp = x15 + off;
    int beg = 0, end = 0, sb = 0;
    float di = 0.f, sq = 0.f;
    float s0 = 0, s1 = 0, s2 = 0, s3 = 0, s4 = 0, s5 = 0, s6 = 0, s7 = 0;
    float a0 = 0, a1 = 0, a2 = 0, a3 = 0, a4 = 0, a5 = 0, a6 = 0, a7 = 0;
    if (act) {
        beg = row_ptr[g]; end = row_ptr[g + 1];
        di = dinv[g];
        sq = sqd[g];
        sb = g * STR + pl;
        float4 sv = xp[sb];
        DEC8(sv, f0, f1, f2, f3)
        s0 = f0.x; s1 = f0.y; s2 = f1.x; s3 = f1.y;
        s4 = f2.x; s5 = f2.y; s6 = f3.x; s7 = f3.y;
        a0 = s0; a1 = s1; a2 = s2; a3 = s3;
        a4 = s4; a5 = s5; a6 = s6; a7 = s7;
    }
    int blkB = row_ptr[n0], blkE = row_ptr[n1];
    for (int W0 = blkB; W0 < blkE; W0 += CH) {
        STAGE_WINDOW
        if (act) GATHER_WINDOW(xp, STR, pl)
    }
    if (!act) return;
    size_t gi = off + sb;
    const float C16 = 0.95f / 16.0f;
    const float C15 = 0.95f / 256.0f;
    const float C14 = 0.95f / 4096.0f;
    const float C13 = 0.95f / 65536.0f;
    const float FC  = 0.05f / 15.0f;
    float t0 = C15 * s0, t1 = C15 * s1, t2 = C15 * s2, t3 = C15 * s3;
    float t4 = C15 * s4, t5 = C15 * s5, t6 = C15 * s6, t7 = C15 * s7;
#define ADD8T(P, CF)                                                        \
    {                                                                       \
        float4 v = ntld_f4((P) + gi);                                       \
        DEC8(v, f0, f1, f2, f3)                                             \
        t0 = fmaf((CF), f0.x, t0); t1 = fmaf((CF), f0.y, t1);               \
        t2 = fmaf((CF), f1.x, t2); t3 = fmaf((CF), f1.y, t3);               \
        t4 = fmaf((CF), f2.x, t4); t5 = fmaf((CF), f2.y, t5);               \
        t6 = fmaf((CF), f3.x, t6); t7 = fmaf((CF), f3.y, t7);               \
    }
    ADD8T(x14p, C14)
    ADD8T(x13p, C13)
    ADD8T(z0p, FC)
#undef ADD8T
    float cd = C16 * di;
    float o0 = fmaf(sq, t0, cd * a0), o1 = fmaf(sq, t1, cd * a1);
    float o2 = fmaf(sq, t2, cd * a2), o3 = fmaf(sq, t3, cd * a3);
    float o4 = fmaf(sq, t4, cd * a4), o5 = fmaf(sq, t5, cd * a5);
    float o6 = fmaf(sq, t6, cd * a6), o7 = fmaf(sq, t7, cd * a7);
    const float4* b4 = (const float4*)(bias + p * 8);
    float4 bb0 = b4[0], bb1 = b4[1];
    float4* op = (float4*)(outp + (size_t)g * CC + p * 8);
    ntst_f4(op,     make_float4(o0 + bb0.x, o1 + bb0.y, o2 + bb0.z, o3 + bb0.w));
    ntst_f4(op + 1, make_float4(o4 + bb1.x, o5 + bb1.y, o6 + bb1.z, o7 + bb1.w));
}

__global__ __launch_bounds__(256) void spmm_final(
    const float4* __restrict__ x15, const float4* __restrict__ x13p,
    const float4* __restrict__ x14p, const float4* __restrict__ z0p,
    const float* __restrict__ bias,
    const int* __restrict__ row_ptr, const int* __restrict__ es,
    const float* __restrict__ dinv, const float* __restrict__ sqd,
    float* __restrict__ outp) {
    __shared__ __align__(16) int sidx[CH + 8];
    int xcd = blockIdx.x & 7;
    int slot = blockIdx.x >> 3;
    int t = threadIdx.x;
    if (xcd < 4) {
        int q0 = xcd * 25000;
        int n0 = q0 + slot * 64;
        int n1 = (n0 + 64 < q0 + 25000) ? (n0 + 64) : (q0 + 25000);
        int g = n0 + (t >> 2);
        int pl = t & 3;
        final_body<4>(sidx, n0, n1, g, g < n1, pl, pl, 0,
                      x15, x13p, x14p, z0p, bias, row_ptr, es, dinv, sqd, outp);
    } else {
        if (slot >= SL2) return;
        int q0 = (xcd - 4) * 25000;
        int n0 = q0 + slot * 256;
        int n1 = (n0 + 256 < q0 + 25000) ? (n0 + 256) : (q0 + 25000);
        int g = n0 + t;
        final_body<1>(sidx, n0, n1, g, g < n1, 0, 4, (size_t)4 * NN,
                      x15, x13p, x14p, z0p, bias, row_ptr, es, dinv, sqd, outp);
    }
}

extern "C" void kernel_launch(void* const* d_in, const int* in_sizes, int n_in,
                              void* d_out, int out_size, void* d_ws, size_t ws_size,
                              hipStream_t stream) {
    const float* feat = (const float*)d_in[0];
    const float* W    = (const float*)d_in[1];
    const float* b    = (const float*)d_in[2];
    const int*   src  = (const int*)d_in[3];
    const int*   dst  = (const int*)d_in[4];
    float* out = (float*)d_out;

    char* p = (char*)d_ws;
    auto alloc = [&](size_t bytes) {
        char* r = p;
        p += (bytes + 255) & ~(size_t)255;
        return r;
    };
    float*   dinv    = (float*)alloc((size_t)NN * sizeof(float));
    float*   sqd     = (float*)alloc((size_t)NN * sizeof(float));
    int*     row_ptr = (int*)alloc((size_t)(NN + 1) * sizeof(int));
    int*     cursor  = (int*)alloc((size_t)NBK * sizeof(int));
    int*     bbase   = (int*)alloc((size_t)NBK * sizeof(int));
    int2*    tmp     = (int2*)alloc((size_t)NBK * TCAP * sizeof(int2));  // 12.6MB
    int*     er_src  = (int*)alloc((size_t)EE * sizeof(int) + 64);       // 4.8MB (+pad for int4 tail)
    float4*  z0      = (float4*)alloc((size_t)NN * 5 * sizeof(float4));  // 8MB
    float4*  xa      = (float4*)alloc((size_t)NN * 5 * sizeof(float4));  // 8MB
    float4*  xb      = (float4*)alloc((size_t)NN * 5 * sizeof(float4));  // 8MB
    float4*  z13     = (float4*)alloc((size_t)NN * 5 * sizeof(float4));  // 8MB
    float4*  z14     = (float4*)alloc((size_t)NN * 5 * sizeof(float4));  // 8MB
    float4*  z15     = (float4*)alloc((size_t)NN * 5 * sizeof(float4));  // 8MB

    curinit_kernel<<<1, 512, 0, stream>>>(cursor);
    sortA_kernel<<<ABLK, 256, 0, stream>>>(src, dst, cursor, tmp);
    bscan_kernel<<<1, 512, 0, stream>>>(cursor, bbase, row_ptr);
    sortB_kernel<<<NBK, 256, 0, stream>>>(tmp, cursor, bbase, dinv, sqd, row_ptr, er_src);
    proj_kernel<<<(NN + 63) / 64, 256, 0, stream>>>((const float4*)feat, W, dinv, z0);

    // z1..z12: ping-pong xa/xb
    const float4* xs = z0;
    for (int j = 0; j < 12; ++j) {
        float4* xd = (j & 1) ? xb : xa;
        spmm_prop<<<GRID8, 256, 0, stream>>>(xs, xd, row_ptr, er_src, dinv);
        xs = xd;
    }
    // z13, z14, z15 into preserved buffers
    spmm_prop<<<GRID8, 256, 0, stream>>>(xs, z13, row_ptr, er_src, dinv);
    spmm_prop<<<GRID8, 256, 0, stream>>>(z13, z14, row_ptr, er_src, dinv);
    spmm_prop<<<GRID8, 256, 0, stream>>>(z14, z15, row_ptr, er_src, dinv);
    // final combine
    spmm_final<<<GRID8, 256, 0, stream>>>(z15, z13, z14, z0, b, row_ptr,
                                          er_src, dinv, sqd, out);
}

// Round 10
// 507.252 us; speedup vs baseline: 9.3706x; 1.0246x over previous
//
#include <hip/hip_runtime.h>
#include <hip/hip_fp16.h>

#define NN 100000
#define EE 1200000
#define DD 64
#define CC 40
#define BSZ 196                          // nodes per sort bucket
#define NBK 512                          // buckets (512*196 = 100352 >= NN)
#define TCAP 3072                        // tmp capacity per bucket (mean 2352, ~15 sigma)
#define EPB 4096                         // edges per phase-A block
#define ABLK ((EE + EPB - 1) / EPB)      // 293

// x layout per state buffer (float4 = 8 halves = 8 channels):
//   Region A [0,4N):  node n -> float4 n*4+q, q=0..3  (channels 0..31, 64B/node = 1 line)
//   Region B [4N,5N): node n -> 4N+n                  (channels 32..39, 16B/node)
// Request-balanced XCD mapping (block b -> XCD b%8):
//   XCD 0..3: region A, dest quarters, 4 lanes/node -> one line-request per edge.
//   XCD 4..7: region B, dest quarters, 1 lane/node.
#define SL1 391                          // ceil(25000/64) G1 slots/XCD
#define SL2 98                           // ceil(25000/256) G2 slots/XCD
#define GRID8 (8 * SL1)                  // 3128 blocks of 256 threads
#define CH 4096                          // staged edge-index window (16KB LDS)

typedef int   v4i __attribute__((ext_vector_type(4)));
typedef float v4f __attribute__((ext_vector_type(4)));
typedef _Float16 v8h __attribute__((ext_vector_type(8)));
typedef _Float16 v4h __attribute__((ext_vector_type(4)));

__device__ __forceinline__ v4i ntld_i4(const int* p) {
    return __builtin_nontemporal_load((const v4i*)p);
}
__device__ __forceinline__ float4 ntld_f4(const float4* p) {
    v4f v = __builtin_nontemporal_load((const v4f*)p);
    return make_float4(v.x, v.y, v.z, v.w);
}
__device__ __forceinline__ void ntst_f4(float4* p, float4 f) {
    v4f v; v.x = f.x; v.y = f.y; v.z = f.z; v.w = f.w;
    __builtin_nontemporal_store(v, (v4f*)p);
}

// ---------- cursor init ----------
__global__ __launch_bounds__(512) void curinit_kernel(int* __restrict__ cursor) {
    int b = threadIdx.x;
    if (b < NBK) cursor[b] = b * TCAP;
}

// ---------- sort phase A: LDS-bin 4096 edges into 512 buckets ----------
__global__ __launch_bounds__(256) void sortA_kernel(const int* __restrict__ src,
                                                    const int* __restrict__ dst,
                                                    int* __restrict__ cursor,
                                                    int2* __restrict__ tmp) {
    __shared__ int2 stg[EPB];                 // 32KB
    __shared__ int hist[NBK], loff[NBK], lcur[NBK], gbase[NBK];  // 8KB
    int t = threadIdx.x;
    long e0 = (long)blockIdx.x * EPB;
    int n = (int)((EE - e0 < EPB) ? (EE - e0) : EPB);
    for (int j = t; j < NBK; j += 256) hist[j] = 0;
    __syncthreads();
    int d[16], sx[16];
#pragma unroll
    for (int j = 0; j < 16; ++j) {
        int i = t + j * 256;
        if (i < n) {
            d[j] = dst[e0 + i];
            sx[j] = src[e0 + i];
            atomicAdd(&hist[d[j] / BSZ], 1);
        } else d[j] = -1;
    }
    __syncthreads();
    int c0 = hist[2 * t], c1 = hist[2 * t + 1];
    int s2 = c0 + c1;
    __syncthreads();
    loff[t] = s2;
    __syncthreads();
    for (int off = 1; off < 256; off <<= 1) {
        int u = (t >= off) ? loff[t - off] : 0;
        __syncthreads();
        loff[t] += u;
        __syncthreads();
    }
    int excl = loff[t] - s2;
    __syncthreads();
    loff[2 * t] = excl;          loff[2 * t + 1] = excl + c0;
    lcur[2 * t] = excl;          lcur[2 * t + 1] = excl + c0;
    gbase[2 * t]     = atomicAdd(&cursor[2 * t], c0);
    gbase[2 * t + 1] = atomicAdd(&cursor[2 * t + 1], c1);
    __syncthreads();
#pragma unroll
    for (int j = 0; j < 16; ++j) {
        if (d[j] >= 0) {
            int b = d[j] / BSZ;
            int p = atomicAdd(&lcur[b], 1);
            stg[p] = make_int2(d[j], sx[j]);
        }
    }
    __syncthreads();
    for (int i = t; i < n; i += 256) {
        int2 r = stg[i];
        int b = r.x / BSZ;
        int pos = gbase[b] + (i - loff[b]);
        if (pos < (b + 1) * TCAP) tmp[pos] = r;  // overflow guard (never hit)
    }
}

// ---------- bucket-base scan ----------
__global__ __launch_bounds__(512) void bscan_kernel(const int* __restrict__ cursor,
                                                    int* __restrict__ bbase,
                                                    int* __restrict__ row_ptr) {
    __shared__ int sm[512];
    int t = threadIdx.x;
    int v = (t < NBK) ? (cursor[t] - t * TCAP) : 0;
    sm[t] = v;
    __syncthreads();
    for (int off = 1; off < 512; off <<= 1) {
        int u = (t >= off) ? sm[t - off] : 0;
        __syncthreads();
        sm[t] += u;
        __syncthreads();
    }
    if (t < NBK) bbase[t] = sm[t] - v;
    if (t == 511) row_ptr[NN] = sm[511];  // == EE
}

// ---------- sort phase B: counting sort within bucket; emit src-only edges ----------
__global__ __launch_bounds__(256) void sortB_kernel(const int2* __restrict__ tmp,
                                                    const int* __restrict__ cursor,
                                                    const int* __restrict__ bbase,
                                                    float* __restrict__ dinv,
                                                    float* __restrict__ sqd,
                                                    int* __restrict__ row_ptr,
                                                    int* __restrict__ er_src) {
    __shared__ int2 se[TCAP];     // 24KB
    __shared__ int so[TCAP];      // 12KB (src only)
    __shared__ int hist[256], lcur[256];
    int b = blockIdx.x;
    int n0 = b * BSZ;
    if (n0 >= NN) return;
    int n1 = n0 + BSZ; if (n1 > NN) n1 = NN;
    int nb = n1 - n0;
    int t = threadIdx.x;
    int cnt = cursor[b] - b * TCAP;
    int base = bbase[b];
    hist[t] = 0;
    __syncthreads();
    for (int i = t; i < cnt; i += 256) {
        int2 r = tmp[b * TCAP + i];
        se[i] = r;
        atomicAdd(&hist[r.x - n0], 1);
    }
    __syncthreads();
    if (t < nb) {
        float dg = (float)(hist[t] + 1);   // +1 self-loop
        dinv[n0 + t] = rsqrtf(dg);
        sqd[n0 + t]  = sqrtf(dg);
    }
    int v = hist[t];
    lcur[t] = v;
    __syncthreads();
    for (int off = 1; off < 256; off <<= 1) {
        int u = (t >= off) ? lcur[t - off] : 0;
        __syncthreads();
        lcur[t] += u;
        __syncthreads();
    }
    int excl = lcur[t] - v;
    __syncthreads();
    lcur[t] = excl;
    if (t < nb) row_ptr[n0 + t] = base + excl;
    __syncthreads();
    for (int i = t; i < cnt; i += 256) {
        int2 r = se[i];
        int ln = r.x - n0;
        int pos = atomicAdd(&lcur[ln], 1);
        so[pos] = r.y;                    // src only (z-space: weights folded out)
    }
    __syncthreads();
    for (int i = t; i < cnt; i += 256) er_src[base + i] = so[i];  // coalesced
}

// ---------- projection via MFMA: z0 = dinv * (feat @ W^T), A/B layout ----------
// Y = F(100K x 64) * W^T(64 x 40). Per wave: 16 nodes, 3 col-tiles x 2 K-chunks of
// mfma_f32_16x16x32_f16. A-frag from f16 LDS tile [64][72]; B-frag straight from
// W rows (8 contiguous fp32 -> f16, registers). Layout-safe: A and B use the same
// k-mapping so any k-permutation in the fragment spec cancels; D layout is the
// HW-verified col=lane&15, row=(lane>>4)*4+reg.
__global__ __launch_bounds__(256) void proj_kernel(const float4* __restrict__ feat4,
                                                   const float* __restrict__ W,
                                                   const float* __restrict__ dinv,
                                                   float4* __restrict__ z0) {
    __shared__ _Float16 fh[64 * 72];   // 9.2KB  (padded: 72 halves/row)
    __shared__ float smO[64 * 50];     // 12.8KB (padded stride 50)
    int t = threadIdx.x;
    int n0 = blockIdx.x * 64;
    // load feat fp32 -> f16 LDS tile
    {
        int node = t >> 2;
        int gn = n0 + node; if (gn >= NN) gn = NN - 1;
        const float4* fr = feat4 + (size_t)gn * 16;
#pragma unroll
        for (int jj = 0; jj < 4; ++jj) {
            int j = (t & 3) + jj * 4;          // float4 index 0..15 (4 d's each)
            float4 v = fr[j];
            v4h pk = { (_Float16)v.x, (_Float16)v.y, (_Float16)v.z, (_Float16)v.w };
            *(v4h*)(&fh[node * 72 + j * 4]) = pk;
        }
    }
    // B fragments in registers (per lane): c = ct*16 + (lane&15), k = kc*32 + (lane>>4)*8 + e
    int lr = t & 63;
    int c_l = lr & 15, q_l = lr >> 4;
    v8h bfr[3][2];
#pragma unroll
    for (int ct = 0; ct < 3; ++ct) {
        int c = ct * 16 + c_l;
#pragma unroll
        for (int kc = 0; kc < 2; ++kc) {
            v8h bv;
            if (c < CC) {
                const float* wp = W + c * 64 + kc * 32 + q_l * 8;
#pragma unroll
                for (int e = 0; e < 8; ++e) bv[e] = (_Float16)wp[e];
            } else {
#pragma unroll
                for (int e = 0; e < 8; ++e) bv[e] = (_Float16)0.f;
            }
            bfr[ct][kc] = bv;
        }
    }
    __syncthreads();
    // A fragments + MFMA
    int wv = t >> 6;
    int row = wv * 16 + c_l;              // node within 64-tile
    v8h a0 = *(const v8h*)(&fh[row * 72 + q_l * 8]);
    v8h a1 = *(const v8h*)(&fh[row * 72 + 32 + q_l * 8]);
#pragma unroll
    for (int ct = 0; ct < 3; ++ct) {
        v4f acc = {0.f, 0.f, 0.f, 0.f};
        acc = __builtin_amdgcn_mfma_f32_16x16x32_f16(a0, bfr[ct][0], acc, 0, 0, 0);
        acc = __builtin_amdgcn_mfma_f32_16x16x32_f16(a1, bfr[ct][1], acc, 0, 0, 0);
#pragma unroll
        for (int i = 0; i < 4; ++i)
            smO[(wv * 16 + 4 * q_l + i) * 50 + ct * 16 + c_l] = acc[i];
    }
    __syncthreads();
    // pack epilogue: region A (q*8 channels) + region B (channels 32..39)
    {
        int r = t >> 2, q = t & 3;
        int g = n0 + r;
        if (g < NN) {
            float dv = dinv[g];
            const float* s = smO + r * 50 + q * 8;
            float4 ov;
            __half2* op = (__half2*)&ov;
            op[0] = __floats2half2_rn(dv * s[0], dv * s[1]);
            op[1] = __floats2half2_rn(dv * s[2], dv * s[3]);
            op[2] = __floats2half2_rn(dv * s[4], dv * s[5]);
            op[3] = __floats2half2_rn(dv * s[6], dv * s[7]);
            z0[(size_t)g * 4 + q] = ov;
        }
    }
    if (t < 64) {
        int g = n0 + t;
        if (g < NN) {
            float dv = dinv[g];
            const float* s = smO + t * 50 + 32;
            float4 ov;
            __half2* op = (__half2*)&ov;
            op[0] = __floats2half2_rn(dv * s[0], dv * s[1]);
            op[1] = __floats2half2_rn(dv * s[2], dv * s[3]);
            op[2] = __floats2half2_rn(dv * s[4], dv * s[5]);
            op[3] = __floats2half2_rn(dv * s[6], dv * s[7]);
            z0[(size_t)4 * NN + g] = ov;
        }
    }
}

// decode float4-of-8-halves into 8 floats
#define DEC8(V, F0, F1, F2, F3)                                             \
    const __half2* hp_##F0 = (const __half2*)&(V);                          \
    float2 F0 = __half22float2(hp_##F0[0]), F1 = __half22float2(hp_##F0[1]);\
    float2 F2 = __half22float2(hp_##F0[2]), F3 = __half22float2(hp_##F0[3]);

#define ACC8U(V)                                                            \
    {                                                                       \
        DEC8(V, f0, f1, f2, f3)                                             \
        a0 += f0.x; a1 += f0.y; a2 += f1.x; a3 += f1.y;                     \
        a4 += f2.x; a5 += f2.y; a6 += f3.x; a7 += f3.y;                     \
    }

// gather loop over the LDS-staged edge window [W0,W1), my row clipped to it.
#define GATHER_WINDOW(XP, STR, PL)                                          \
    {                                                                       \
        int lo = (beg > W0) ? beg : W0;                                     \
        int hi = (end < W1) ? end : W1;                                     \
        int e = lo;                                                         \
        for (; e + 8 <= hi; e += 8) {                                       \
            int s0 = sidx[e - A0 + 0], s1 = sidx[e - A0 + 1];               \
            int s2 = sidx[e - A0 + 2], s3 = sidx[e - A0 + 3];               \
            int s4 = sidx[e - A0 + 4], s5 = sidx[e - A0 + 5];               \
            int s6 = sidx[e - A0 + 6], s7 = sidx[e - A0 + 7];               \
            float4 v0 = (XP)[s0 * (STR) + (PL)];                            \
            float4 v1 = (XP)[s1 * (STR) + (PL)];                            \
            float4 v2 = (XP)[s2 * (STR) + (PL)];                            \
            float4 v3 = (XP)[s3 * (STR) + (PL)];                            \
            float4 v4 = (XP)[s4 * (STR) + (PL)];                            \
            float4 v5 = (XP)[s5 * (STR) + (PL)];                            \
            float4 v6 = (XP)[s6 * (STR) + (PL)];                            \
            float4 v7 = (XP)[s7 * (STR) + (PL)];                            \
            ACC8U(v0); ACC8U(v1); ACC8U(v2); ACC8U(v3);                     \
            ACC8U(v4); ACC8U(v5); ACC8U(v6); ACC8U(v7);                     \
        }                                                                   \
        if (e + 4 <= hi) {                                                  \
            int s0 = sidx[e - A0 + 0], s1 = sidx[e - A0 + 1];               \
            int s2 = sidx[e - A0 + 2], s3 = sidx[e - A0 + 3];               \
            float4 v0 = (XP)[s0 * (STR) + (PL)];                            \
            float4 v1 = (XP)[s1 * (STR) + (PL)];                            \
            float4 v2 = (XP)[s2 * (STR) + (PL)];                            \
            float4 v3 = (XP)[s3 * (STR) + (PL)];                            \
            ACC8U(v0); ACC8U(v1); ACC8U(v2); ACC8U(v3);                     \
            e += 4;                                                         \
        }                                                                   \
        for (; e < hi; ++e) {                                               \
            int s = sidx[e - A0];                                           \
            float4 v = (XP)[s * (STR) + (PL)];                              \
            ACC8U(v);                                                       \
        }                                                                   \
    }

// stage es[W0..W1) into LDS with bulk nt int4 loads (no L1/L2 allocation)
#define STAGE_WINDOW                                                        \
    int W1 = (W0 + CH < blkE) ? (W0 + CH) : blkE;                           \
    int A0 = W0 & ~3;                                                       \
    __syncthreads();                                                        \
    for (int i = A0 + (int)threadIdx.x * 4; i < W1; i += 1024) {            \
        *(v4i*)(sidx + (i - A0)) = ntld_i4(es + i);                         \
    }                                                                       \
    __syncthreads();

// ---------- SpMM propagate body: z_out[d] = dinv[d]^2 * (z[d] + sum z[src]) ----------
template <int STR>
__device__ __forceinline__ void prop_body(
    int* sidx, int n0, int n1, int g, bool act, int pl, size_t off,
    const float4* __restrict__ x, float4* __restrict__ x_out,
    const int* __restrict__ row_ptr, const int* __restrict__ es,
    const float* __restrict__ dinv) {
    const float4* xp = x + off;
    int beg = 0, end = 0, sb = 0;
    float w2 = 0.f;
    float a0 = 0, a1 = 0, a2 = 0, a3 = 0, a4 = 0, a5 = 0, a6 = 0, a7 = 0;
    if (act) {
        beg = row_ptr[g]; end = row_ptr[g + 1];
        float di = dinv[g];
        w2 = di * di;
        sb = g * STR + pl;
        float4 sv = xp[sb];
        DEC8(sv, f0, f1, f2, f3)
        a0 = f0.x; a1 = f0.y; a2 = f1.x; a3 = f1.y;
        a4 = f2.x; a5 = f2.y; a6 = f3.x; a7 = f3.y;
    }
    int blkB = row_ptr[n0], blkE = row_ptr[n1];
    for (int W0 = blkB; W0 < blkE; W0 += CH) {
        STAGE_WINDOW
        if (act) GATHER_WINDOW(xp, STR, pl)
    }
    if (act) {
        float4 ov;
        __half2* op = (__half2*)&ov;
        op[0] = __floats2half2_rn(w2 * a0, w2 * a1);
        op[1] = __floats2half2_rn(w2 * a2, w2 * a3);
        op[2] = __floats2half2_rn(w2 * a4, w2 * a5);
        op[3] = __floats2half2_rn(w2 * a6, w2 * a7);
        ntst_f4(x_out + off + sb, ov);   // nt: keep gather slice unpolluted
    }
}

__global__ __launch_bounds__(256) void spmm_prop(
    const float4* __restrict__ x, float4* __restrict__ x_out,
    const int* __restrict__ row_ptr, const int* __restrict__ es,
    const float* __restrict__ dinv) {
    __shared__ __align__(16) int sidx[CH + 8];
    int xcd = blockIdx.x & 7;
    int slot = blockIdx.x >> 3;
    int t = threadIdx.x;
    if (xcd < 4) {
        int q0 = xcd * 25000;
        int n0 = q0 + slot * 64;
        int n1 = (n0 + 64 < q0 + 25000) ? (n0 + 64) : (q0 + 25000);
        int g = n0 + (t >> 2);
        prop_body<4>(sidx, n0, n1, g, g < n1, t & 3, 0,
                     x, x_out, row_ptr, es, dinv);
    } else {
        if (slot >= SL2) return;
        int q0 = (xcd - 4) * 25000;
        int n0 = q0 + slot * 256;
        int n1 = (n0 + 256 < q0 + 25000) ? (n0 + 256) : (q0 + 25000);
        int g = n0 + t;
        prop_body<1>(sidx, n0, n1, g, g < n1, 0, (size_t)4 * NN,
                     x, x_out, row_ptr, es, dinv);
    }
}

// ---------- final: acc = sum z15 (incl self); out = C16*dinv*acc
//            + sqd*(C15*z15 + C14*z14 + C13*z13 + FC*z0) + bias ----------
template <int STR>
__device__ __forceinline__ void final_body(
    int* sidx, int n0, int n1, int g, bool act, int pl, int p, size_t off,
    const float4* __restrict__ x15, const float4* __restrict__ x13p,
    const float4* __restrict__ x14p, const float4* __restrict__ z0p,
    const float* __restrict__ bias,
    const int* __restrict__ row_ptr, const int* __restrict__ es,
    const float* __restrict__ dinv, const float* __restrict__ sqd,
    float* __restrict__ outp) {
    const float4* xp = x15 + off;
    int beg = 0, end = 0, sb = 0;
    float di = 0.f, sq = 0.f;
    float s0 = 0, s1 = 0, s2 = 0, s3 = 0, s4 = 0, s5 = 0, s6 = 0, s7 = 0;
    float a0 = 0, a1 = 0, a2 = 0, a3 = 0, a4 = 0, a5 = 0, a6 = 0, a7 = 0;
    if (act) {
        beg = row_ptr[g]; end = row_ptr[g + 1];
        di = dinv[g];
        sq = sqd[g];
        sb = g * STR + pl;
        float4 sv = xp[sb];
        DEC8(sv, f0, f1, f2, f3)
        s0 = f0.x; s1 = f0.y; s2 = f1.x; s3 = f1.y;
        s4 = f2.x; s5 = f2.y; s6 = f3.x; s7 = f3.y;
        a0 = s0; a1 = s1; a2 = s2; a3 = s3;
        a4 = s4; a5 = s5; a6 = s6; a7 = s7;
    }
    int blkB = row_ptr[n0], blkE = row_ptr[n1];
    for (int W0 = blkB; W0 < blkE; W0 += CH) {
        STAGE_WINDOW
        if (act) GATHER_WINDOW(xp, STR, pl)
    }
    if (!act) return;
    size_t gi = off + sb;
    const float C16 = 0.95f / 16.0f;
    const float C15 = 0.95f / 256.0f;
    const float C14 = 0.95f / 4096.0f;
    const float C13 = 0.95f / 65536.0f;
    const float FC  = 0.05f / 15.0f;
    float t0 = C15 * s0, t1 = C15 * s1, t2 = C15 * s2, t3 = C15 * s3;
    float t4 = C15 * s4, t5 = C15 * s5, t6 = C15 * s6, t7 = C15 * s7;
#define ADD8T(P, CF)                                                        \
    {                                                                       \
        float4 v = ntld_f4((P) + gi);                                       \
        DEC8(v, f0, f1, f2, f3)                                             \
        t0 = fmaf((CF), f0.x, t0); t1 = fmaf((CF), f0.y, t1);               \
        t2 = fmaf((CF), f1.x, t2); t3 = fmaf((CF), f1.y, t3);               \
        t4 = fmaf((CF), f2.x, t4); t5 = fmaf((CF), f2.y, t5);               \
        t6 = fmaf((CF), f3.x, t6); t7 = fmaf((CF), f3.y, t7);               \
    }
    ADD8T(x14p, C14)
    ADD8T(x13p, C13)
    ADD8T(z0p, FC)
#undef ADD8T
    float cd = C16 * di;
    float o0 = fmaf(sq, t0, cd * a0), o1 = fmaf(sq, t1, cd * a1);
    float o2 = fmaf(sq, t2, cd * a2), o3 = fmaf(sq, t3, cd * a3);
    float o4 = fmaf(sq, t4, cd * a4), o5 = fmaf(sq, t5, cd * a5);
    float o6 = fmaf(sq, t6, cd * a6), o7 = fmaf(sq, t7, cd * a7);
    const float4* b4 = (const float4*)(bias + p * 8);
    float4 bb0 = b4[0], bb1 = b4[1];
    float4* op = (float4*)(outp + (size_t)g * CC + p * 8);
    ntst_f4(op,     make_float4(o0 + bb0.x, o1 + bb0.y, o2 + bb0.z, o3 + bb0.w));
    ntst_f4(op + 1, make_float4(o4 + bb1.x, o5 + bb1.y, o6 + bb1.z, o7 + bb1.w));
}

__global__ __launch_bounds__(256) void spmm_final(
    const float4* __restrict__ x15, const float4* __restrict__ x13p,
    const float4* __restrict__ x14p, const float4* __restrict__ z0p,
    const float* __restrict__ bias,
    const int* __restrict__ row_ptr, const int* __restrict__ es,
    const float* __restrict__ dinv, const float* __restrict__ sqd,
    float* __restrict__ outp) {
    __shared__ __align__(16) int sidx[CH + 8];
    int xcd = blockIdx.x & 7;
    int slot = blockIdx.x >> 3;
    int t = threadIdx.x;
    if (xcd < 4) {
        int q0 = xcd * 25000;
        int n0 = q0 + slot * 64;
        int n1 = (n0 + 64 < q0 + 25000) ? (n0 + 64) : (q0 + 25000);
        int g = n0 + (t >> 2);
        int pl = t & 3;
        final_body<4>(sidx, n0, n1, g, g < n1, pl, pl, 0,
                      x15, x13p, x14p, z0p, bias, row_ptr, es, dinv, sqd, outp);
    } else {
        if (slot >= SL2) return;
        int q0 = (xcd - 4) * 25000;
        int n0 = q0 + slot * 256;
        int n1 = (n0 + 256 < q0 + 25000) ? (n0 + 256) : (q0 + 25000);
        int g = n0 + t;
        final_body<1>(sidx, n0, n1, g, g < n1, 0, 4, (size_t)4 * NN,
                      x15, x13p, x14p, z0p, bias, row_ptr, es, dinv, sqd, outp);
    }
}

extern "C" void kernel_launch(void* const* d_in, const int* in_sizes, int n_in,
                              void* d_out, int out_size, void* d_ws, size_t ws_size,
                              hipStream_t stream) {
    const float* feat = (const float*)d_in[0];
    const float* W    = (const float*)d_in[1];
    const float* b    = (const float*)d_in[2];
    const int*   src  = (const int*)d_in[3];
    const int*   dst  = (const int*)d_in[4];
    float* out = (float*)d_out;

    char* p = (char*)d_ws;
    auto alloc = [&](size_t bytes) {
        char* r = p;
        p += (bytes + 255) & ~(size_t)255;
        return r;
    };
    float*   dinv    = (float*)alloc((size_t)NN * sizeof(float));
    float*   sqd     = (float*)alloc((size_t)NN * sizeof(float));
    int*     row_ptr = (int*)alloc((size_t)(NN + 1) * sizeof(int));
    int*     cursor  = (int*)alloc((size_t)NBK * sizeof(int));
    int*     bbase   = (int*)alloc((size_t)NBK * sizeof(int));
    int2*    tmp     = (int2*)alloc((size_t)NBK * TCAP * sizeof(int2));  // 12.6MB
    int*     er_src  = (int*)alloc((size_t)EE * sizeof(int) + 64);       // 4.8MB (+pad for int4 tail)
    float4*  z0      = (float4*)alloc((size_t)NN * 5 * sizeof(float4));  // 8MB
    float4*  xa      = (float4*)alloc((size_t)NN * 5 * sizeof(float4));  // 8MB
    float4*  xb      = (float4*)alloc((size_t)NN * 5 * sizeof(float4));  // 8MB
    float4*  z13     = (float4*)alloc((size_t)NN * 5 * sizeof(float4));  // 8MB
    float4*  z14     = (float4*)alloc((size_t)NN * 5 * sizeof(float4));  // 8MB
    float4*  z15     = (float4*)alloc((size_t)NN * 5 * sizeof(float4));  // 8MB

    curinit_kernel<<<1, 512, 0, stream>>>(cursor);
    sortA_kernel<<<ABLK, 256, 0, stream>>>(src, dst, cursor, tmp);
    bscan_kernel<<<1, 512, 0, stream>>>(cursor, bbase, row_ptr);
    sortB_kernel<<<NBK, 256, 0, stream>>>(tmp, cursor, bbase, dinv, sqd, row_ptr, er_src);
    proj_kernel<<<(NN + 63) / 64, 256, 0, stream>>>((const float4*)feat, W, dinv, z0);

    // z1..z12: ping-pong xa/xb
    const float4* xs = z0;
    for (int j = 0; j < 12; ++j) {
        float4* xd = (j & 1) ? xb : xa;
        spmm_prop<<<GRID8, 256, 0, stream>>>(xs, xd, row_ptr, er_src, dinv);
        xs = xd;
    }
    // z13, z14, z15 into preserved buffers
    spmm_prop<<<GRID8, 256, 0, stream>>>(xs, z13, row_ptr, er_src, dinv);
    spmm_prop<<<GRID8, 256, 0, stream>>>(z13, z14, row_ptr, er_src, dinv);
    spmm_prop<<<GRID8, 256, 0, stream>>>(z14, z15, row_ptr, er_src, dinv);
    // final combine
    spmm_final<<<GRID8, 256, 0, stream>>>(z15, z13, z14, z0, b, row_ptr,
                                          er_src, dinv, sqd, out);
}